// Round 1
// baseline (370.458 us; speedup 1.0000x reference)
//
#include <hip/hip_runtime.h>
#include <hip/hip_bf16.h>

#define BATCH 2
#define CH 256
#define NH 4
#define HD 64
#define NGROUP 8
#define CPG 32
#define NTOK 4096
#define EPSV 1e-5f

typedef __attribute__((ext_vector_type(8))) short short8;
typedef __attribute__((ext_vector_type(4))) float float4v;

__device__ __forceinline__ unsigned short f2bf(float f) {
    union { float f; unsigned u; } v; v.f = f;
    unsigned r = v.u + 0x7FFF + ((v.u >> 16) & 1);
    return (unsigned short)(r >> 16);
}

// ---------------- GroupNorm: partial sums ----------------
__global__ void gn_partial(const float* __restrict__ x, float* __restrict__ psum,
                           float* __restrict__ psq) {
    int s = blockIdx.x;   // 16 slices
    int g = blockIdx.y;   // 8 groups
    int b = blockIdx.z;   // 2 batches
    const float* base = x + ((size_t)(b * CH + g * CPG)) * NTOK + (size_t)s * 8192;
    int t = threadIdx.x;
    float sum = 0.f, sq = 0.f;
    const float4v* p4 = (const float4v*)base;
    for (int i = 0; i < 8; ++i) {
        float4v v = p4[t + i * 256];
        for (int j = 0; j < 4; ++j) { sum += v[j]; sq += v[j] * v[j]; }
    }
    for (int off = 32; off; off >>= 1) {
        sum += __shfl_down(sum, off, 64);
        sq  += __shfl_down(sq,  off, 64);
    }
    __shared__ float ls[8];
    int wave = t >> 6, lane = t & 63;
    if (lane == 0) { ls[wave * 2] = sum; ls[wave * 2 + 1] = sq; }
    __syncthreads();
    if (t == 0) {
        float S = 0.f, Q = 0.f;
        for (int w = 0; w < 4; ++w) { S += ls[w * 2]; Q += ls[w * 2 + 1]; }
        int idx = (b * NGROUP + g) * 16 + s;
        psum[idx] = S; psq[idx] = Q;
    }
}

// ---------------- GroupNorm: finalize stats ----------------
__global__ void gn_stats(const float* __restrict__ psum, const float* __restrict__ psq,
                         float* __restrict__ stats) {
    int t = threadIdx.x;
    if (t < BATCH * NGROUP) {
        float S = 0.f, Q = 0.f;
        for (int s = 0; s < 16; ++s) { S += psum[t * 16 + s]; Q += psq[t * 16 + s]; }
        const float M = (float)(CPG * NTOK);
        float mean = S / M;
        float var  = Q / M - mean * mean;
        stats[t * 2]     = mean;
        stats[t * 2 + 1] = rsqrtf(var + EPSV);
    }
}

// ---------------- GroupNorm: normalize + transpose to hT[b][n][c] (bf16) ----------------
__global__ void gn_norm(const float* __restrict__ x, const float* __restrict__ nw,
                        const float* __restrict__ nb_, const float* __restrict__ stats,
                        unsigned short* __restrict__ hT) {
    int c = blockIdx.y, b = blockIdx.z;
    int n0 = blockIdx.x * 2048 + threadIdx.x * 8;
    int g = c >> 5;
    float mean = stats[(b * NGROUP + g) * 2];
    float inv  = stats[(b * NGROUP + g) * 2 + 1];
    float w  = nw[c] * inv;
    float bb = nb_[c] - mean * w;
    const float4v* px = (const float4v*)(x + ((size_t)(b * CH + c)) * NTOK + n0);
    unsigned short* ph = hT + ((size_t)b * NTOK + n0) * CH + c;
    for (int i = 0; i < 2; ++i) {
        float4v v = px[i];
        for (int j = 0; j < 4; ++j) ph[(size_t)(i * 4 + j) * CH] = f2bf(v[j] * w + bb);
    }
}

// ---------------- QKV GEMM (bf16 MFMA), scatter to qT/kT/v ----------------
__global__ __launch_bounds__(256) void qkv_gemm(const unsigned short* __restrict__ hT,
        const float* __restrict__ qkv_w, const float* __restrict__ qkv_b,
        unsigned short* __restrict__ qT, unsigned short* __restrict__ kT,
        unsigned short* __restrict__ vv) {
    int nb = blockIdx.x;       // 0..63 (n tile of 64)
    int ob = blockIdx.y;       // 0..11 (o tile of 64)
    int b  = blockIdx.z;
    int t = threadIdx.x;
    int wave = t >> 6, lane = t & 63;
    int l15 = lane & 15, quad = lane >> 4;
    int o0 = ob * 64 + wave * 16;

    short8 aW[8];
    {
        const float* wr = qkv_w + (size_t)(o0 + l15) * CH + quad * 8;
        for (int kc = 0; kc < 8; ++kc) {
            short8 a;
            for (int j = 0; j < 8; ++j) a[j] = (short)f2bf(wr[kc * 32 + j]);
            aW[kc] = a;
        }
    }
    float4v acc[4];
    for (int nt = 0; nt < 4; ++nt) for (int r = 0; r < 4; ++r) acc[nt][r] = 0.f;

    for (int kc = 0; kc < 8; ++kc) {
        for (int nt = 0; nt < 4; ++nt) {
            const short8* pb = (const short8*)(hT +
                ((size_t)b * NTOK + nb * 64 + nt * 16 + l15) * CH + kc * 32 + quad * 8);
            acc[nt] = __builtin_amdgcn_mfma_f32_16x16x32_bf16(aW[kc], *pb, acc[nt], 0, 0, 0);
        }
    }
    for (int nt = 0; nt < 4; ++nt) {
        int n = nb * 64 + nt * 16 + l15;
        for (int r = 0; r < 4; ++r) {
            int o = o0 + quad * 4 + r;
            float val = acc[nt][r] + qkv_b[o];
            unsigned short bv = f2bf(val);
            int cch = o & 255;
            int seg = o >> 8;          // 0=q, 1=k, 2=v
            int hh = cch >> 6, ci = cch & 63;
            if (seg == 0)      qT[(((size_t)b * NH + hh) * NTOK + n) * HD + ci] = bv;
            else if (seg == 1) kT[(((size_t)b * NH + hh) * NTOK + n) * HD + ci] = bv;
            else               vv[(((size_t)b * NH + hh) * HD + ci) * NTOK + n] = bv;
        }
    }
}

// ---------------- Flash attention (bf16 MFMA, online softmax) ----------------
__global__ __launch_bounds__(256) void attn_kernel(const unsigned short* __restrict__ qT,
        const unsigned short* __restrict__ kT, const unsigned short* __restrict__ vv,
        unsigned short* __restrict__ oT) {
    int nb = blockIdx.x;  // 0..63 : 64 query rows per block
    int h  = blockIdx.y;
    int b  = blockIdx.z;
    int t = threadIdx.x, wave = t >> 6, lane = t & 63;
    int l15 = lane & 15, quad = lane >> 4;
    int n0 = nb * 64 + wave * 16;

    const unsigned short* qbh = qT + ((size_t)(b * NH + h)) * NTOK * HD;
    const unsigned short* kbh = kT + ((size_t)(b * NH + h)) * NTOK * HD;
    const unsigned short* vbh = vv + ((size_t)(b * NH + h)) * HD * NTOK;

    __shared__ __align__(16) unsigned short pbuf[4][16 * 72];
    unsigned short* myp = pbuf[wave];

    short8 aQ0 = *(const short8*)(qbh + (size_t)(n0 + l15) * HD + quad * 8);
    short8 aQ1 = *(const short8*)(qbh + (size_t)(n0 + l15) * HD + 32 + quad * 8);

    float m_i[4], l_i[4];
    float4v o_acc[4];
    for (int r = 0; r < 4; ++r) { m_i[r] = -1e30f; l_i[r] = 0.f; }
    for (int ct = 0; ct < 4; ++ct) for (int r = 0; r < 4; ++r) o_acc[ct][r] = 0.f;

    for (int ms = 0; ms < NTOK; ms += 64) {
        float4v s[4];
        for (int mt = 0; mt < 4; ++mt) {
            const short8* bk0 = (const short8*)(kbh + (size_t)(ms + mt * 16 + l15) * HD + quad * 8);
            const short8* bk1 = (const short8*)(kbh + (size_t)(ms + mt * 16 + l15) * HD + 32 + quad * 8);
            float4v z;
            for (int r = 0; r < 4; ++r) z[r] = 0.f;
            z = __builtin_amdgcn_mfma_f32_16x16x32_bf16(aQ0, *bk0, z, 0, 0, 0);
            z = __builtin_amdgcn_mfma_f32_16x16x32_bf16(aQ1, *bk1, z, 0, 0, 0);
            s[mt] = z;
        }
        float mnew[4], alpha[4];
        for (int r = 0; r < 4; ++r) {
            float mx = -1e30f;
            for (int mt = 0; mt < 4; ++mt) { s[mt][r] *= 0.125f; mx = fmaxf(mx, s[mt][r]); }
            for (int off = 1; off < 16; off <<= 1) mx = fmaxf(mx, __shfl_xor(mx, off, 64));
            mnew[r] = fmaxf(m_i[r], mx);
        }
        for (int r = 0; r < 4; ++r) {
            alpha[r] = __expf(m_i[r] - mnew[r]);
            m_i[r] = mnew[r];
            float srow = 0.f;
            for (int mt = 0; mt < 4; ++mt) {
                float p = __expf(s[mt][r] - mnew[r]);
                s[mt][r] = p;
                srow += p;
            }
            for (int off = 1; off < 16; off <<= 1) srow += __shfl_xor(srow, off, 64);
            l_i[r] = l_i[r] * alpha[r] + srow;
        }
        for (int ct = 0; ct < 4; ++ct)
            for (int r = 0; r < 4; ++r) o_acc[ct][r] *= alpha[r];

        // P (C-layout) -> LDS -> A-layout
        for (int mt = 0; mt < 4; ++mt)
            for (int r = 0; r < 4; ++r)
                myp[(quad * 4 + r) * 72 + mt * 16 + l15] = f2bf(s[mt][r]);
        asm volatile("s_waitcnt lgkmcnt(0)" ::: "memory");
        short8 aP0 = *(const short8*)(myp + l15 * 72 + quad * 8);
        short8 aP1 = *(const short8*)(myp + l15 * 72 + 32 + quad * 8);
        for (int ct = 0; ct < 4; ++ct) {
            const short8* bv0 = (const short8*)(vbh + (size_t)(ct * 16 + l15) * NTOK + ms + quad * 8);
            const short8* bv1 = (const short8*)(vbh + (size_t)(ct * 16 + l15) * NTOK + ms + 32 + quad * 8);
            o_acc[ct] = __builtin_amdgcn_mfma_f32_16x16x32_bf16(aP0, *bv0, o_acc[ct], 0, 0, 0);
            o_acc[ct] = __builtin_amdgcn_mfma_f32_16x16x32_bf16(aP1, *bv1, o_acc[ct], 0, 0, 0);
        }
        asm volatile("s_waitcnt lgkmcnt(0)" ::: "memory");
    }
    for (int ct = 0; ct < 4; ++ct) {
        for (int r = 0; r < 4; ++r) {
            int n = n0 + quad * 4 + r;
            int cg = h * HD + ct * 16 + l15;
            float val = o_acc[ct][r] / l_i[r];
            oT[((size_t)b * NTOK + n) * CH + cg] = f2bf(val);
        }
    }
}

// ---------------- Proj GEMM + bias + residual ----------------
__global__ __launch_bounds__(256) void proj_gemm(const unsigned short* __restrict__ oT,
        const float* __restrict__ proj_w, const float* __restrict__ proj_b,
        const float* __restrict__ x, float* __restrict__ out) {
    int nb = blockIdx.x;   // 0..63
    int cb = blockIdx.y;   // 0..3
    int b  = blockIdx.z;
    int t = threadIdx.x, wave = t >> 6, lane = t & 63;
    int l15 = lane & 15, quad = lane >> 4;
    int c0 = cb * 64 + wave * 16;

    short8 aW[8];
    {
        const float* wr = proj_w + (size_t)(c0 + l15) * CH + quad * 8;
        for (int kc = 0; kc < 8; ++kc) {
            short8 a;
            for (int j = 0; j < 8; ++j) a[j] = (short)f2bf(wr[kc * 32 + j]);
            aW[kc] = a;
        }
    }
    float4v acc[4];
    for (int nt = 0; nt < 4; ++nt) for (int r = 0; r < 4; ++r) acc[nt][r] = 0.f;

    for (int kc = 0; kc < 8; ++kc) {
        for (int nt = 0; nt < 4; ++nt) {
            const short8* pb = (const short8*)(oT +
                ((size_t)b * NTOK + nb * 64 + nt * 16 + l15) * CH + kc * 32 + quad * 8);
            acc[nt] = __builtin_amdgcn_mfma_f32_16x16x32_bf16(aW[kc], *pb, acc[nt], 0, 0, 0);
        }
    }
    for (int nt = 0; nt < 4; ++nt) {
        int n = nb * 64 + nt * 16 + l15;
        for (int r = 0; r < 4; ++r) {
            int cc = c0 + quad * 4 + r;
            size_t idx = ((size_t)(b * CH + cc)) * NTOK + n;
            out[idx] = acc[nt][r] + proj_b[cc] + x[idx];
        }
    }
}

extern "C" void kernel_launch(void* const* d_in, const int* in_sizes, int n_in,
                              void* d_out, int out_size, void* d_ws, size_t ws_size,
                              hipStream_t stream) {
    const float* x      = (const float*)d_in[0];
    const float* norm_w = (const float*)d_in[1];
    const float* norm_b = (const float*)d_in[2];
    const float* qkv_w  = (const float*)d_in[3];
    const float* qkv_b  = (const float*)d_in[4];
    const float* proj_w = (const float*)d_in[5];
    const float* proj_b = (const float*)d_in[6];
    float* out = (float*)d_out;

    char* ws = (char*)d_ws;
    float* psum  = (float*)ws;                 // 256 floats
    float* psq   = (float*)(ws + 1024);        // 256 floats
    float* stats = (float*)(ws + 2048);        // 32 floats
    unsigned short* hT = (unsigned short*)(ws + 4096);
    const size_t sz = (size_t)BATCH * NTOK * CH;   // 2,097,152 elements per array
    unsigned short* qT = hT + sz;
    unsigned short* kT = qT + sz;
    unsigned short* vv = kT + sz;
    unsigned short* oT = vv + sz;

    gn_partial<<<dim3(16, NGROUP, BATCH), dim3(256), 0, stream>>>(x, psum, psq);
    gn_stats<<<dim3(1), dim3(64), 0, stream>>>(psum, psq, stats);
    gn_norm<<<dim3(2, CH, BATCH), dim3(256), 0, stream>>>(x, norm_w, norm_b, stats, hT);
    qkv_gemm<<<dim3(64, 12, BATCH), dim3(256), 0, stream>>>(hT, qkv_w, qkv_b, qT, kT, vv);
    attn_kernel<<<dim3(64, NH, BATCH), dim3(256), 0, stream>>>(qT, kT, vv, oT);
    proj_gemm<<<dim3(64, 4, BATCH), dim3(256), 0, stream>>>(oT, proj_w, proj_b, x, out);
}

// Round 3
// 359.252 us; speedup vs baseline: 1.0312x; 1.0312x over previous
//
#include <hip/hip_runtime.h>
#include <hip/hip_bf16.h>

#define BATCH 2
#define CH 256
#define NH 4
#define HD 64
#define NGROUP 8
#define CPG 32
#define NTOK 4096
#define EPSV 1e-5f
// scale = hd^-0.5 = 0.125, folded with log2(e) so P = exp2(q'.k)
#define QSCALE 0.1803368801111204f

typedef __attribute__((ext_vector_type(8))) short short8;
typedef __attribute__((ext_vector_type(4))) float float4v;

__device__ __forceinline__ unsigned short f2bf(float f) {
    union { float f; unsigned u; } v; v.f = f;
    unsigned r = v.u + 0x7FFF + ((v.u >> 16) & 1);
    return (unsigned short)(r >> 16);
}
__device__ __forceinline__ unsigned short f2bf_fast(float f) {
    union { float f; unsigned u; } v; v.f = f;
    return (unsigned short)((v.u + 0x8000u) >> 16);
}
__device__ __forceinline__ float bf2f(unsigned short u) {
    union { unsigned u; float f; } v; v.u = ((unsigned)u) << 16;
    return v.f;
}

// ---------------- weight convert: f32 -> bf16 (q part pre-scaled) ----------------
__global__ void wcvt(const float* __restrict__ qkv_w, const float* __restrict__ qkv_b,
                     const float* __restrict__ proj_w,
                     unsigned short* __restrict__ wq, float* __restrict__ bq,
                     unsigned short* __restrict__ wp) {
    int idx = blockIdx.x * 256 + threadIdx.x;
    int stride = gridDim.x * 256;
    for (int i = idx; i < 3 * CH * CH; i += stride) {
        float f = qkv_w[i];
        if (i < CH * CH) f *= QSCALE;
        wq[i] = f2bf(f);
    }
    for (int i = idx; i < CH * CH; i += stride) wp[i] = f2bf(proj_w[i]);
    for (int i = idx; i < 3 * CH; i += stride) {
        float f = qkv_b[i];
        if (i < CH) f *= QSCALE;
        bq[i] = f;
    }
}

// ---------------- GroupNorm: partial sums ----------------
__global__ void gn_partial(const float* __restrict__ x, float* __restrict__ psum,
                           float* __restrict__ psq) {
    int s = blockIdx.x;   // 16 slices
    int g = blockIdx.y;   // 8 groups
    int b = blockIdx.z;   // 2 batches
    const float* base = x + ((size_t)(b * CH + g * CPG)) * NTOK + (size_t)s * 8192;
    int t = threadIdx.x;
    float sum = 0.f, sq = 0.f;
    const float4v* p4 = (const float4v*)base;
    for (int i = 0; i < 8; ++i) {
        float4v v = p4[t + i * 256];
        for (int j = 0; j < 4; ++j) { sum += v[j]; sq += v[j] * v[j]; }
    }
    for (int off = 32; off; off >>= 1) {
        sum += __shfl_down(sum, off, 64);
        sq  += __shfl_down(sq,  off, 64);
    }
    __shared__ float ls[8];
    int wave = t >> 6, lane = t & 63;
    if (lane == 0) { ls[wave * 2] = sum; ls[wave * 2 + 1] = sq; }
    __syncthreads();
    if (t == 0) {
        float S = 0.f, Q = 0.f;
        for (int w = 0; w < 4; ++w) { S += ls[w * 2]; Q += ls[w * 2 + 1]; }
        int idx = (b * NGROUP + g) * 16 + s;
        psum[idx] = S; psq[idx] = Q;
    }
}

// ---------------- GroupNorm: finalize stats ----------------
__global__ void gn_stats(const float* __restrict__ psum, const float* __restrict__ psq,
                         float* __restrict__ stats) {
    int t = threadIdx.x;
    if (t < BATCH * NGROUP) {
        float S = 0.f, Q = 0.f;
        for (int s = 0; s < 16; ++s) { S += psum[t * 16 + s]; Q += psq[t * 16 + s]; }
        const float M = (float)(CPG * NTOK);
        float mean = S / M;
        float var  = Q / M - mean * mean;
        stats[t * 2]     = mean;
        stats[t * 2 + 1] = rsqrtf(var + EPSV);
    }
}

// ---------------- GroupNorm: normalize + transpose to hT[b][n][c] (bf16) ----------------
// wave-uniform c (8 channels per wave), lanes along n for coalesced reads
__global__ void gn_norm(const float* __restrict__ x, const float* __restrict__ nw,
                        const float* __restrict__ nb_, const float* __restrict__ stats,
                        unsigned short* __restrict__ hT) {
    int t = threadIdx.x;
    int n = blockIdx.x * 64 + (t & 63);
    int cb = blockIdx.y * 32 + (t >> 6) * 8;
    int b = blockIdx.z;
    short8 h8;
    for (int j = 0; j < 8; ++j) {
        int c = cb + j;
        int g = c >> 5;
        float mean = stats[(b * NGROUP + g) * 2];
        float inv  = stats[(b * NGROUP + g) * 2 + 1];
        float w  = nw[c] * inv;
        float bb = nb_[c] - mean * w;
        float v = x[((size_t)(b * CH + c)) * NTOK + n];
        h8[j] = (short)f2bf(v * w + bb);
    }
    *(short8*)(hT + ((size_t)b * NTOK + n) * CH + cb) = h8;
}

// ---------------- QKV GEMM (bf16 MFMA), scatter to qT/kT/v ----------------
__global__ __launch_bounds__(256) void qkv_gemm(const unsigned short* __restrict__ hT,
        const unsigned short* __restrict__ wq, const float* __restrict__ bq,
        unsigned short* __restrict__ qT, unsigned short* __restrict__ kT,
        unsigned short* __restrict__ vv) {
    int nb = blockIdx.x;       // 0..63 (n tile of 64)
    int ob = blockIdx.y;       // 0..11 (o tile of 64)
    int b  = blockIdx.z;
    int t = threadIdx.x;
    int wave = t >> 6, lane = t & 63;
    int l15 = lane & 15, quad = lane >> 4;
    int o0 = ob * 64 + wave * 16;

    short8 aW[8];
    {
        const unsigned short* wr = wq + (size_t)(o0 + l15) * CH + quad * 8;
        for (int kc = 0; kc < 8; ++kc) aW[kc] = *(const short8*)(wr + kc * 32);
    }
    float4v acc[4];
    for (int nt = 0; nt < 4; ++nt) for (int r = 0; r < 4; ++r) acc[nt][r] = 0.f;

    for (int kc = 0; kc < 8; ++kc) {
        for (int nt = 0; nt < 4; ++nt) {
            const short8* pb = (const short8*)(hT +
                ((size_t)b * NTOK + nb * 64 + nt * 16 + l15) * CH + kc * 32 + quad * 8);
            acc[nt] = __builtin_amdgcn_mfma_f32_16x16x32_bf16(aW[kc], *pb, acc[nt], 0, 0, 0);
        }
    }
    for (int nt = 0; nt < 4; ++nt) {
        int n = nb * 64 + nt * 16 + l15;
        for (int r = 0; r < 4; ++r) {
            int o = o0 + quad * 4 + r;
            float val = acc[nt][r] + bq[o];
            unsigned short bv = f2bf(val);
            int cch = o & 255;
            int seg = o >> 8;          // 0=q (pre-scaled), 1=k, 2=v
            int hh = cch >> 6, ci = cch & 63;
            if (seg == 0)      qT[(((size_t)b * NH + hh) * NTOK + n) * HD + ci] = bv;
            else if (seg == 1) kT[(((size_t)b * NH + hh) * NTOK + n) * HD + ci] = bv;
            else               vv[(((size_t)b * NH + hh) * HD + ci) * NTOK + n] = bv;
        }
    }
}

// ---------------- Flash attention, no-max exp2 softmax, split-KV x2 ----------------
__global__ __launch_bounds__(256) void attn_kernel(const unsigned short* __restrict__ qT,
        const unsigned short* __restrict__ kT, const unsigned short* __restrict__ vv,
        unsigned short* __restrict__ op0, unsigned short* __restrict__ op1,
        float* __restrict__ lp0, float* __restrict__ lp1) {
    int nb = blockIdx.x;          // 0..63 : 64 query rows per block
    int h  = blockIdx.y;
    int zb = blockIdx.z;          // 0..3 : (b, split)
    int sp = zb & 1, b = zb >> 1;
    int t = threadIdx.x, wave = t >> 6, lane = t & 63;
    int l15 = lane & 15, quad = lane >> 4;
    int n0 = nb * 64 + wave * 16;
    int kv0 = sp * (NTOK / 2);

    unsigned short* opart = sp ? op1 : op0;
    float* lpart = sp ? lp1 : lp0;

    const unsigned short* qbh = qT + ((size_t)(b * NH + h)) * NTOK * HD;
    const unsigned short* kbh = kT + ((size_t)(b * NH + h)) * NTOK * HD;
    const unsigned short* vbh = vv + ((size_t)(b * NH + h)) * HD * NTOK;

    __shared__ __align__(16) unsigned short pbuf[4][16 * 72];
    unsigned short* myp = pbuf[wave];

    short8 aQ0 = *(const short8*)(qbh + (size_t)(n0 + l15) * HD + quad * 8);
    short8 aQ1 = *(const short8*)(qbh + (size_t)(n0 + l15) * HD + 32 + quad * 8);

    float l_p[4];
    float4v o_acc[4];
    for (int r = 0; r < 4; ++r) l_p[r] = 0.f;
    for (int ct = 0; ct < 4; ++ct) for (int r = 0; r < 4; ++r) o_acc[ct][r] = 0.f;

    for (int ms = kv0; ms < kv0 + NTOK / 2; ms += 64) {
        float4v s[4];
#pragma unroll
        for (int mt = 0; mt < 4; ++mt) {
            const short8* bk0 = (const short8*)(kbh + (size_t)(ms + mt * 16 + l15) * HD + quad * 8);
            const short8* bk1 = (const short8*)(kbh + (size_t)(ms + mt * 16 + l15) * HD + 32 + quad * 8);
            float4v z;
            for (int r = 0; r < 4; ++r) z[r] = 0.f;
            z = __builtin_amdgcn_mfma_f32_16x16x32_bf16(aQ0, *bk0, z, 0, 0, 0);
            z = __builtin_amdgcn_mfma_f32_16x16x32_bf16(aQ1, *bk1, z, 0, 0, 0);
            s[mt] = z;
        }
        // P = exp2(s)  (scale*log2e folded into q); defer denominator
#pragma unroll
        for (int mt = 0; mt < 4; ++mt)
            for (int r = 0; r < 4; ++r)
                s[mt][r] = __builtin_amdgcn_exp2f(s[mt][r]);
#pragma unroll
        for (int r = 0; r < 4; ++r)
            l_p[r] += (s[0][r] + s[1][r]) + (s[2][r] + s[3][r]);
        // P (C-layout) -> LDS -> A-layout
#pragma unroll
        for (int mt = 0; mt < 4; ++mt)
            for (int r = 0; r < 4; ++r)
                myp[(quad * 4 + r) * 72 + mt * 16 + l15] = f2bf_fast(s[mt][r]);
        asm volatile("s_waitcnt lgkmcnt(0)" ::: "memory");
        short8 aP0 = *(const short8*)(myp + l15 * 72 + quad * 8);
        short8 aP1 = *(const short8*)(myp + l15 * 72 + 32 + quad * 8);
#pragma unroll
        for (int ct = 0; ct < 4; ++ct) {
            const short8* bv0 = (const short8*)(vbh + (size_t)(ct * 16 + l15) * NTOK + ms + quad * 8);
            const short8* bv1 = (const short8*)(vbh + (size_t)(ct * 16 + l15) * NTOK + ms + 32 + quad * 8);
            o_acc[ct] = __builtin_amdgcn_mfma_f32_16x16x32_bf16(aP0, *bv0, o_acc[ct], 0, 0, 0);
            o_acc[ct] = __builtin_amdgcn_mfma_f32_16x16x32_bf16(aP1, *bv1, o_acc[ct], 0, 0, 0);
        }
        asm volatile("s_waitcnt lgkmcnt(0)" ::: "memory");
    }
    // reduce l over the 16 lanes holding each row's columns
    for (int r = 0; r < 4; ++r)
        for (int off = 1; off < 16; off <<= 1)
            l_p[r] += __shfl_xor(l_p[r], off, 64);
    // store unnormalized partial O (bf16) + l
    for (int ct = 0; ct < 4; ++ct) {
        for (int r = 0; r < 4; ++r) {
            int n = n0 + quad * 4 + r;
            int cg = h * HD + ct * 16 + l15;
            opart[((size_t)b * NTOK + n) * CH + cg] = f2bf(o_acc[ct][r]);
        }
    }
    if (l15 == 0) {
        for (int r = 0; r < 4; ++r)
            lpart[((size_t)(b * NH + h)) * NTOK + n0 + quad * 4 + r] = l_p[r];
    }
}

// ---------------- combine split-KV partials ----------------
__global__ void attn_combine(const unsigned short* __restrict__ op0,
                             const unsigned short* __restrict__ op1,
                             const float* __restrict__ lp0, const float* __restrict__ lp1,
                             unsigned short* __restrict__ oT) {
    int idx = blockIdx.x * 256 + threadIdx.x;   // chunk of 8 channels
    int c0 = (idx & 31) * 8;
    int n  = (idx >> 5) & (NTOK - 1);
    int b  = idx >> 17;
    int h  = c0 >> 6;
    float ls = lp0[((size_t)(b * NH + h)) * NTOK + n] + lp1[((size_t)(b * NH + h)) * NTOK + n];
    float rinv = 1.0f / ls;
    size_t base = ((size_t)b * NTOK + n) * CH + c0;
    short8 o0 = *(const short8*)(op0 + base);
    short8 o1 = *(const short8*)(op1 + base);
    short8 out;
    for (int j = 0; j < 8; ++j) {
        float f = bf2f((unsigned short)o0[j]) + bf2f((unsigned short)o1[j]);
        out[j] = (short)f2bf(f * rinv);
    }
    *(short8*)(oT + base) = out;
}

// ---------------- Proj GEMM + bias + residual ----------------
__global__ __launch_bounds__(256) void proj_gemm(const unsigned short* __restrict__ oT,
        const unsigned short* __restrict__ wp, const float* __restrict__ proj_b,
        const float* __restrict__ x, float* __restrict__ out) {
    int nb = blockIdx.x;   // 0..63
    int cb = blockIdx.y;   // 0..3
    int b  = blockIdx.z;
    int t = threadIdx.x, wave = t >> 6, lane = t & 63;
    int l15 = lane & 15, quad = lane >> 4;
    int c0 = cb * 64 + wave * 16;

    short8 aW[8];
    {
        const unsigned short* wr = wp + (size_t)(c0 + l15) * CH + quad * 8;
        for (int kc = 0; kc < 8; ++kc) aW[kc] = *(const short8*)(wr + kc * 32);
    }
    float4v acc[4];
    for (int nt = 0; nt < 4; ++nt) for (int r = 0; r < 4; ++r) acc[nt][r] = 0.f;

    for (int kc = 0; kc < 8; ++kc) {
        for (int nt = 0; nt < 4; ++nt) {
            const short8* pb = (const short8*)(oT +
                ((size_t)b * NTOK + nb * 64 + nt * 16 + l15) * CH + kc * 32 + quad * 8);
            acc[nt] = __builtin_amdgcn_mfma_f32_16x16x32_bf16(aW[kc], *pb, acc[nt], 0, 0, 0);
        }
    }
    for (int nt = 0; nt < 4; ++nt) {
        int n = nb * 64 + nt * 16 + l15;
        for (int r = 0; r < 4; ++r) {
            int cc = c0 + quad * 4 + r;
            size_t idx = ((size_t)(b * CH + cc)) * NTOK + n;
            out[idx] = acc[nt][r] + proj_b[cc] + x[idx];
        }
    }
}

extern "C" void kernel_launch(void* const* d_in, const int* in_sizes, int n_in,
                              void* d_out, int out_size, void* d_ws, size_t ws_size,
                              hipStream_t stream) {
    const float* x      = (const float*)d_in[0];
    const float* norm_w = (const float*)d_in[1];
    const float* norm_b = (const float*)d_in[2];
    const float* qkv_w  = (const float*)d_in[3];
    const float* qkv_b  = (const float*)d_in[4];
    const float* proj_w = (const float*)d_in[5];
    const float* proj_b = (const float*)d_in[6];
    float* out = (float*)d_out;

    char* ws = (char*)d_ws;
    float* psum  = (float*)ws;                       // 256 f
    float* psq   = (float*)(ws + 1024);              // 256 f
    float* stats = (float*)(ws + 2048);              // 32 f
    float* bqs   = (float*)(ws + 4096);              // 768 f
    unsigned short* wqb = (unsigned short*)(ws + 8192);        // 3*256*256 bf16
    unsigned short* wpb = (unsigned short*)(ws + 401408);      // 256*256 bf16
    float* lp0 = (float*)(ws + 532480);              // 2*4*4096 f
    float* lp1 = (float*)(ws + 663552);
    const size_t MB4 = 4194304;
    unsigned short* hT = (unsigned short*)(ws + 1048576);      // aliased with op0
    unsigned short* op0 = hT;                                  // hT dead after qkv_gemm
    unsigned short* qT = (unsigned short*)(ws + 1048576 + MB4);
    unsigned short* kT = (unsigned short*)(ws + 1048576 + 2 * MB4);
    unsigned short* vv = (unsigned short*)(ws + 1048576 + 3 * MB4);
    unsigned short* oT = (unsigned short*)(ws + 1048576 + 4 * MB4);
    unsigned short* op1 = (unsigned short*)(ws + 1048576 + 5 * MB4);

    wcvt<<<dim3(256), dim3(256), 0, stream>>>(qkv_w, qkv_b, proj_w, wqb, bqs, wpb);
    gn_partial<<<dim3(16, NGROUP, BATCH), dim3(256), 0, stream>>>(x, psum, psq);
    gn_stats<<<dim3(1), dim3(64), 0, stream>>>(psum, psq, stats);
    gn_norm<<<dim3(64, 8, BATCH), dim3(256), 0, stream>>>(x, norm_w, norm_b, stats, hT);
    qkv_gemm<<<dim3(64, 12, BATCH), dim3(256), 0, stream>>>(hT, wqb, bqs, qT, kT, vv);
    attn_kernel<<<dim3(64, NH, BATCH * 2), dim3(256), 0, stream>>>(qT, kT, vv, op0, op1, lp0, lp1);
    attn_combine<<<dim3(1024), dim3(256), 0, stream>>>(op0, op1, lp0, lp1, oT);
    proj_gemm<<<dim3(64, 4, BATCH), dim3(256), 0, stream>>>(oT, wpb, proj_b, x, out);
}

// Round 4
// 209.528 us; speedup vs baseline: 1.7681x; 1.7146x over previous
//
#include <hip/hip_runtime.h>
#include <hip/hip_bf16.h>

#define BATCH 2
#define CH 256
#define NH 4
#define HD 64
#define NGROUP 8
#define CPG 32
#define NTOK 4096
#define EPSV 1e-5f
// scale = hd^-0.5 = 0.125, folded with log2(e) so P = exp2(q'.k)
#define QSCALE 0.1803368801111204f

typedef __attribute__((ext_vector_type(8))) short short8;
typedef __attribute__((ext_vector_type(4))) float float4v;

__device__ __forceinline__ unsigned short f2bf(float f) {
    union { float f; unsigned u; } v; v.f = f;
    unsigned r = v.u + 0x7FFF + ((v.u >> 16) & 1);
    return (unsigned short)(r >> 16);
}
__device__ __forceinline__ unsigned short f2bf_fast(float f) {
    union { float f; unsigned u; } v; v.f = f;
    return (unsigned short)((v.u + 0x8000u) >> 16);
}
__device__ __forceinline__ float bf2f(unsigned short u) {
    union { unsigned u; float f; } v; v.u = ((unsigned)u) << 16;
    return v.f;
}

// ---------------- weight convert: f32 -> bf16 (q part pre-scaled) ----------------
__global__ void wcvt(const float* __restrict__ qkv_w, const float* __restrict__ qkv_b,
                     const float* __restrict__ proj_w,
                     unsigned short* __restrict__ wq, float* __restrict__ bq,
                     unsigned short* __restrict__ wp) {
    int idx = blockIdx.x * 256 + threadIdx.x;
    int stride = gridDim.x * 256;
    for (int i = idx; i < 3 * CH * CH; i += stride) {
        float f = qkv_w[i];
        if (i < CH * CH) f *= QSCALE;
        wq[i] = f2bf(f);
    }
    for (int i = idx; i < CH * CH; i += stride) wp[i] = f2bf(proj_w[i]);
    for (int i = idx; i < 3 * CH; i += stride) {
        float f = qkv_b[i];
        if (i < CH) f *= QSCALE;
        bq[i] = f;
    }
}

// ---------------- GroupNorm: partial sums ----------------
__global__ void gn_partial(const float* __restrict__ x, float* __restrict__ psum,
                           float* __restrict__ psq) {
    int s = blockIdx.x;   // 16 slices
    int g = blockIdx.y;   // 8 groups
    int b = blockIdx.z;   // 2 batches
    const float* base = x + ((size_t)(b * CH + g * CPG)) * NTOK + (size_t)s * 8192;
    int t = threadIdx.x;
    float sum = 0.f, sq = 0.f;
    const float4v* p4 = (const float4v*)base;
    for (int i = 0; i < 8; ++i) {
        float4v v = p4[t + i * 256];
        for (int j = 0; j < 4; ++j) { sum += v[j]; sq += v[j] * v[j]; }
    }
    for (int off = 32; off; off >>= 1) {
        sum += __shfl_down(sum, off, 64);
        sq  += __shfl_down(sq,  off, 64);
    }
    __shared__ float ls[8];
    int wave = t >> 6, lane = t & 63;
    if (lane == 0) { ls[wave * 2] = sum; ls[wave * 2 + 1] = sq; }
    __syncthreads();
    if (t == 0) {
        float S = 0.f, Q = 0.f;
        for (int w = 0; w < 4; ++w) { S += ls[w * 2]; Q += ls[w * 2 + 1]; }
        int idx = (b * NGROUP + g) * 16 + s;
        psum[idx] = S; psq[idx] = Q;
    }
}

// ---------------- GroupNorm: finalize stats ----------------
__global__ void gn_stats(const float* __restrict__ psum, const float* __restrict__ psq,
                         float* __restrict__ stats) {
    int t = threadIdx.x;
    if (t < BATCH * NGROUP) {
        float S = 0.f, Q = 0.f;
        for (int s = 0; s < 16; ++s) { S += psum[t * 16 + s]; Q += psq[t * 16 + s]; }
        const float M = (float)(CPG * NTOK);
        float mean = S / M;
        float var  = Q / M - mean * mean;
        stats[t * 2]     = mean;
        stats[t * 2 + 1] = rsqrtf(var + EPSV);
    }
}

// ---------------- GroupNorm: normalize + transpose to hT[b][n][c] (bf16) ----------------
__global__ void gn_norm(const float* __restrict__ x, const float* __restrict__ nw,
                        const float* __restrict__ nb_, const float* __restrict__ stats,
                        unsigned short* __restrict__ hT) {
    int t = threadIdx.x;
    int n = blockIdx.x * 64 + (t & 63);
    int cb = blockIdx.y * 32 + (t >> 6) * 8;
    int b = blockIdx.z;
    short8 h8;
    for (int j = 0; j < 8; ++j) {
        int c = cb + j;
        int g = c >> 5;
        float mean = stats[(b * NGROUP + g) * 2];
        float inv  = stats[(b * NGROUP + g) * 2 + 1];
        float w  = nw[c] * inv;
        float bb = nb_[c] - mean * w;
        float v = x[((size_t)(b * CH + c)) * NTOK + n];
        h8[j] = (short)f2bf(v * w + bb);
    }
    *(short8*)(hT + ((size_t)b * NTOK + n) * CH + cb) = h8;
}

// ---------------- QKV GEMM (bf16 MFMA), scatter to qT/kT/v ----------------
__global__ __launch_bounds__(256) void qkv_gemm(const unsigned short* __restrict__ hT,
        const unsigned short* __restrict__ wq, const float* __restrict__ bq,
        unsigned short* __restrict__ qT, unsigned short* __restrict__ kT,
        unsigned short* __restrict__ vv) {
    int nb = blockIdx.x;       // 0..63 (n tile of 64)
    int ob = blockIdx.y;       // 0..11 (o tile of 64)
    int b  = blockIdx.z;
    int t = threadIdx.x;
    int wave = t >> 6, lane = t & 63;
    int l15 = lane & 15, quad = lane >> 4;
    int o0 = ob * 64 + wave * 16;

    short8 aW[8];
    {
        const unsigned short* wr = wq + (size_t)(o0 + l15) * CH + quad * 8;
        for (int kc = 0; kc < 8; ++kc) aW[kc] = *(const short8*)(wr + kc * 32);
    }
    float4v acc[4];
    for (int nt = 0; nt < 4; ++nt) for (int r = 0; r < 4; ++r) acc[nt][r] = 0.f;

    for (int kc = 0; kc < 8; ++kc) {
        for (int nt = 0; nt < 4; ++nt) {
            const short8* pb = (const short8*)(hT +
                ((size_t)b * NTOK + nb * 64 + nt * 16 + l15) * CH + kc * 32 + quad * 8);
            acc[nt] = __builtin_amdgcn_mfma_f32_16x16x32_bf16(aW[kc], *pb, acc[nt], 0, 0, 0);
        }
    }
    for (int nt = 0; nt < 4; ++nt) {
        int n = nb * 64 + nt * 16 + l15;
        for (int r = 0; r < 4; ++r) {
            int o = o0 + quad * 4 + r;
            float val = acc[nt][r] + bq[o];
            unsigned short bv = f2bf(val);
            int cch = o & 255;
            int seg = o >> 8;          // 0=q (pre-scaled), 1=k, 2=v
            int hh = cch >> 6, ci = cch & 63;
            if (seg == 0)      qT[(((size_t)b * NH + hh) * NTOK + n) * HD + ci] = bv;
            else if (seg == 1) kT[(((size_t)b * NH + hh) * NTOK + n) * HD + ci] = bv;
            else               vv[(((size_t)b * NH + hh) * HD + ci) * NTOK + n] = bv;
        }
    }
}

// ---------------- Flash attention: LDS-staged K/V, Q=128/block, split-KV x2 ----------------
__global__ __launch_bounds__(256) void attn_kernel(const unsigned short* __restrict__ qT,
        const unsigned short* __restrict__ kT, const unsigned short* __restrict__ vv,
        unsigned short* __restrict__ op0, unsigned short* __restrict__ op1,
        float* __restrict__ lp0, float* __restrict__ lp1) {
    int nb = blockIdx.x;          // 0..31 : 128 query rows per block
    int h  = blockIdx.y;
    int zb = blockIdx.z;          // 0..3 : (b, split)
    int sp = zb & 1, b = zb >> 1;
    int t = threadIdx.x, wave = t >> 6, lane = t & 63;
    int l15 = lane & 15, quad = lane >> 4;
    int n0 = nb * 128 + wave * 32;     // wave owns 2 m-tiles of 16 rows
    int kv0 = sp * (NTOK / 2);

    unsigned short* opart = sp ? op1 : op0;
    float* lpart = sp ? lp1 : lp0;

    const unsigned short* qbh = qT + ((size_t)(b * NH + h)) * NTOK * HD;
    const unsigned short* kbh = kT + ((size_t)(b * NH + h)) * NTOK * HD;
    const unsigned short* vbh = vv + ((size_t)(b * NH + h)) * HD * NTOK;

    // stride-72 padded tiles: 64 rows x 64 cols bf16
    __shared__ __align__(16) unsigned short kbuf[64 * 72];
    __shared__ __align__(16) unsigned short vbuf[64 * 72];
    __shared__ __align__(16) unsigned short pbuf[4][16 * 72];
    unsigned short* myp = pbuf[wave];

    short8 aQ[2][2];
    for (int mt = 0; mt < 2; ++mt) {
        aQ[mt][0] = *(const short8*)(qbh + (size_t)(n0 + mt * 16 + l15) * HD + quad * 8);
        aQ[mt][1] = *(const short8*)(qbh + (size_t)(n0 + mt * 16 + l15) * HD + 32 + quad * 8);
    }

    float l_p[2][4];
    float4v o_acc[2][4];
    for (int mt = 0; mt < 2; ++mt) {
        for (int r = 0; r < 4; ++r) l_p[mt][r] = 0.f;
        for (int ct = 0; ct < 4; ++ct) for (int r = 0; r < 4; ++r) o_acc[mt][ct][r] = 0.f;
    }

    for (int ms = kv0; ms < kv0 + NTOK / 2; ms += 64) {
        __syncthreads();   // previous iteration's reads done before overwrite
        // cooperative staging: K tile [64 keys][64 hd], V tile [64 hd][64 keys]
#pragma unroll
        for (int p = 0; p < 2; ++p) {
            int slot = p * 256 + t;
            int r = slot >> 3, c = slot & 7;
            short8 kd = *(const short8*)(kbh + (size_t)(ms + r) * HD + c * 8);
            *(short8*)(kbuf + r * 72 + c * 8) = kd;
            short8 vd = *(const short8*)(vbh + (size_t)r * NTOK + ms + c * 8);
            *(short8*)(vbuf + r * 72 + c * 8) = vd;
        }
        __syncthreads();

        // QK^T: S[mt][nt] for 2 m-tiles x 4 n-tiles (64 keys)
        float4v s[2][4];
#pragma unroll
        for (int nt = 0; nt < 4; ++nt) {
            short8 bk0 = *(const short8*)(kbuf + (nt * 16 + l15) * 72 + quad * 8);
            short8 bk1 = *(const short8*)(kbuf + (nt * 16 + l15) * 72 + 32 + quad * 8);
#pragma unroll
            for (int mt = 0; mt < 2; ++mt) {
                float4v z;
                for (int r = 0; r < 4; ++r) z[r] = 0.f;
                z = __builtin_amdgcn_mfma_f32_16x16x32_bf16(aQ[mt][0], bk0, z, 0, 0, 0);
                z = __builtin_amdgcn_mfma_f32_16x16x32_bf16(aQ[mt][1], bk1, z, 0, 0, 0);
                s[mt][nt] = z;
            }
        }
        // P = exp2(s); defer denominator
#pragma unroll
        for (int mt = 0; mt < 2; ++mt) {
#pragma unroll
            for (int nt = 0; nt < 4; ++nt)
                for (int r = 0; r < 4; ++r)
                    s[mt][nt][r] = __builtin_amdgcn_exp2f(s[mt][nt][r]);
            for (int r = 0; r < 4; ++r)
                l_p[mt][r] += (s[mt][0][r] + s[mt][1][r]) + (s[mt][2][r] + s[mt][3][r]);
        }
        // V B-fragments (shared across m-tiles) + P round-trip per m-tile
        short8 aP[2][2];
#pragma unroll
        for (int mt = 0; mt < 2; ++mt) {
#pragma unroll
            for (int nt = 0; nt < 4; ++nt)
                for (int r = 0; r < 4; ++r)
                    myp[(quad * 4 + r) * 72 + nt * 16 + l15] = f2bf_fast(s[mt][nt][r]);
            asm volatile("s_waitcnt lgkmcnt(0)" ::: "memory");
            aP[mt][0] = *(const short8*)(myp + l15 * 72 + quad * 8);
            aP[mt][1] = *(const short8*)(myp + l15 * 72 + 32 + quad * 8);
            asm volatile("s_waitcnt lgkmcnt(0)" ::: "memory");
        }
#pragma unroll
        for (int ct = 0; ct < 4; ++ct) {
            short8 bv0 = *(const short8*)(vbuf + (ct * 16 + l15) * 72 + quad * 8);
            short8 bv1 = *(const short8*)(vbuf + (ct * 16 + l15) * 72 + 32 + quad * 8);
#pragma unroll
            for (int mt = 0; mt < 2; ++mt) {
                o_acc[mt][ct] = __builtin_amdgcn_mfma_f32_16x16x32_bf16(aP[mt][0], bv0, o_acc[mt][ct], 0, 0, 0);
                o_acc[mt][ct] = __builtin_amdgcn_mfma_f32_16x16x32_bf16(aP[mt][1], bv1, o_acc[mt][ct], 0, 0, 0);
            }
        }
    }
    // reduce l over the 16 lanes holding each row's columns
    for (int mt = 0; mt < 2; ++mt)
        for (int r = 0; r < 4; ++r)
            for (int off = 1; off < 16; off <<= 1)
                l_p[mt][r] += __shfl_xor(l_p[mt][r], off, 64);
    // store unnormalized partial O (bf16) + l
    for (int mt = 0; mt < 2; ++mt) {
        for (int ct = 0; ct < 4; ++ct) {
            for (int r = 0; r < 4; ++r) {
                int n = n0 + mt * 16 + quad * 4 + r;
                int cg = h * HD + ct * 16 + l15;
                opart[((size_t)b * NTOK + n) * CH + cg] = f2bf(o_acc[mt][ct][r]);
            }
        }
        if (l15 == 0) {
            for (int r = 0; r < 4; ++r)
                lpart[((size_t)(b * NH + h)) * NTOK + n0 + mt * 16 + quad * 4 + r] = l_p[mt][r];
        }
    }
}

// ---------------- combine split-KV partials ----------------
__global__ void attn_combine(const unsigned short* __restrict__ op0,
                             const unsigned short* __restrict__ op1,
                             const float* __restrict__ lp0, const float* __restrict__ lp1,
                             unsigned short* __restrict__ oT) {
    int idx = blockIdx.x * 256 + threadIdx.x;   // chunk of 8 channels
    int c0 = (idx & 31) * 8;
    int n  = (idx >> 5) & (NTOK - 1);
    int b  = idx >> 17;
    int h  = c0 >> 6;
    float ls = lp0[((size_t)(b * NH + h)) * NTOK + n] + lp1[((size_t)(b * NH + h)) * NTOK + n];
    float rinv = 1.0f / ls;
    size_t base = ((size_t)b * NTOK + n) * CH + c0;
    short8 o0 = *(const short8*)(op0 + base);
    short8 o1 = *(const short8*)(op1 + base);
    short8 out;
    for (int j = 0; j < 8; ++j) {
        float f = bf2f((unsigned short)o0[j]) + bf2f((unsigned short)o1[j]);
        out[j] = (short)f2bf(f * rinv);
    }
    *(short8*)(oT + base) = out;
}

// ---------------- Proj GEMM + bias + residual ----------------
__global__ __launch_bounds__(256) void proj_gemm(const unsigned short* __restrict__ oT,
        const unsigned short* __restrict__ wp, const float* __restrict__ proj_b,
        const float* __restrict__ x, float* __restrict__ out) {
    int nb = blockIdx.x;   // 0..63
    int cb = blockIdx.y;   // 0..3
    int b  = blockIdx.z;
    int t = threadIdx.x, wave = t >> 6, lane = t & 63;
    int l15 = lane & 15, quad = lane >> 4;
    int c0 = cb * 64 + wave * 16;

    short8 aW[8];
    {
        const unsigned short* wr = wp + (size_t)(c0 + l15) * CH + quad * 8;
        for (int kc = 0; kc < 8; ++kc) aW[kc] = *(const short8*)(wr + kc * 32);
    }
    float4v acc[4];
    for (int nt = 0; nt < 4; ++nt) for (int r = 0; r < 4; ++r) acc[nt][r] = 0.f;

    for (int kc = 0; kc < 8; ++kc) {
        for (int nt = 0; nt < 4; ++nt) {
            const short8* pb = (const short8*)(oT +
                ((size_t)b * NTOK + nb * 64 + nt * 16 + l15) * CH + kc * 32 + quad * 8);
            acc[nt] = __builtin_amdgcn_mfma_f32_16x16x32_bf16(aW[kc], *pb, acc[nt], 0, 0, 0);
        }
    }
    for (int nt = 0; nt < 4; ++nt) {
        int n = nb * 64 + nt * 16 + l15;
        for (int r = 0; r < 4; ++r) {
            int cc = c0 + quad * 4 + r;
            size_t idx = ((size_t)(b * CH + cc)) * NTOK + n;
            out[idx] = acc[nt][r] + proj_b[cc] + x[idx];
        }
    }
}

extern "C" void kernel_launch(void* const* d_in, const int* in_sizes, int n_in,
                              void* d_out, int out_size, void* d_ws, size_t ws_size,
                              hipStream_t stream) {
    const float* x      = (const float*)d_in[0];
    const float* norm_w = (const float*)d_in[1];
    const float* norm_b = (const float*)d_in[2];
    const float* qkv_w  = (const float*)d_in[3];
    const float* qkv_b  = (const float*)d_in[4];
    const float* proj_w = (const float*)d_in[5];
    const float* proj_b = (const float*)d_in[6];
    float* out = (float*)d_out;

    char* ws = (char*)d_ws;
    float* psum  = (float*)ws;                       // 256 f
    float* psq   = (float*)(ws + 1024);              // 256 f
    float* stats = (float*)(ws + 2048);              // 32 f
    float* bqs   = (float*)(ws + 4096);              // 768 f
    unsigned short* wqb = (unsigned short*)(ws + 8192);        // 3*256*256 bf16
    unsigned short* wpb = (unsigned short*)(ws + 401408);      // 256*256 bf16
    float* lp0 = (float*)(ws + 532480);              // 2*4*4096 f
    float* lp1 = (float*)(ws + 663552);
    const size_t MB4 = 4194304;
    unsigned short* hT = (unsigned short*)(ws + 1048576);      // aliased with op0
    unsigned short* op0 = hT;                                  // hT dead after qkv_gemm
    unsigned short* qT = (unsigned short*)(ws + 1048576 + MB4);
    unsigned short* kT = (unsigned short*)(ws + 1048576 + 2 * MB4);
    unsigned short* vv = (unsigned short*)(ws + 1048576 + 3 * MB4);
    unsigned short* oT = (unsigned short*)(ws + 1048576 + 4 * MB4);
    unsigned short* op1 = (unsigned short*)(ws + 1048576 + 5 * MB4);

    wcvt<<<dim3(256), dim3(256), 0, stream>>>(qkv_w, qkv_b, proj_w, wqb, bqs, wpb);
    gn_partial<<<dim3(16, NGROUP, BATCH), dim3(256), 0, stream>>>(x, psum, psq);
    gn_stats<<<dim3(1), dim3(64), 0, stream>>>(psum, psq, stats);
    gn_norm<<<dim3(64, 8, BATCH), dim3(256), 0, stream>>>(x, norm_w, norm_b, stats, hT);
    qkv_gemm<<<dim3(64, 12, BATCH), dim3(256), 0, stream>>>(hT, wqb, bqs, qT, kT, vv);
    attn_kernel<<<dim3(32, NH, BATCH * 2), dim3(256), 0, stream>>>(qT, kT, vv, op0, op1, lp0, lp1);
    attn_combine<<<dim3(1024), dim3(256), 0, stream>>>(op0, op1, lp0, lp1, oT);
    proj_gemm<<<dim3(64, 4, BATCH), dim3(256), 0, stream>>>(oT, wpb, proj_b, x, out);
}

// Round 5
// 181.753 us; speedup vs baseline: 2.0383x; 1.1528x over previous
//
#include <hip/hip_runtime.h>
#include <hip/hip_bf16.h>

#define BATCH 2
#define CH 256
#define NH 4
#define HD 64
#define NGROUP 8
#define CPG 32
#define NTOK 4096
#define EPSV 1e-5f
// scale = hd^-0.5 = 0.125, folded with log2(e) so P = exp2(q'.k)
#define QSCALE 0.1803368801111204f
#define NSPLIT 4

typedef __attribute__((ext_vector_type(8))) short short8;
typedef __attribute__((ext_vector_type(4))) short s4bf;
typedef __attribute__((ext_vector_type(4))) float float4v;

__device__ __forceinline__ unsigned short f2bf(float f) {
    union { float f; unsigned u; } v; v.f = f;
    unsigned r = v.u + 0x7FFF + ((v.u >> 16) & 1);
    return (unsigned short)(r >> 16);
}
__device__ __forceinline__ unsigned short f2bf_fast(float f) {
    union { float f; unsigned u; } v; v.f = f;
    return (unsigned short)((v.u + 0x8000u) >> 16);
}
__device__ __forceinline__ float bf2f(unsigned short u) {
    union { unsigned u; float f; } v; v.u = ((unsigned)u) << 16;
    return v.f;
}

// ---------------- weight convert: f32 -> bf16 (q part pre-scaled) ----------------
__global__ void wcvt(const float* __restrict__ qkv_w, const float* __restrict__ qkv_b,
                     const float* __restrict__ proj_w,
                     unsigned short* __restrict__ wq, float* __restrict__ bq,
                     unsigned short* __restrict__ wp) {
    int idx = blockIdx.x * 256 + threadIdx.x;
    int stride = gridDim.x * 256;
    for (int i = idx; i < 3 * CH * CH; i += stride) {
        float f = qkv_w[i];
        if (i < CH * CH) f *= QSCALE;
        wq[i] = f2bf(f);
    }
    for (int i = idx; i < CH * CH; i += stride) wp[i] = f2bf(proj_w[i]);
    for (int i = idx; i < 3 * CH; i += stride) {
        float f = qkv_b[i];
        if (i < CH) f *= QSCALE;
        bq[i] = f;
    }
}

// ---------------- GroupNorm: partial sums ----------------
__global__ void gn_partial(const float* __restrict__ x, float* __restrict__ psum,
                           float* __restrict__ psq) {
    int s = blockIdx.x;   // 16 slices
    int g = blockIdx.y;   // 8 groups
    int b = blockIdx.z;   // 2 batches
    const float* base = x + ((size_t)(b * CH + g * CPG)) * NTOK + (size_t)s * 8192;
    int t = threadIdx.x;
    float sum = 0.f, sq = 0.f;
    const float4v* p4 = (const float4v*)base;
    for (int i = 0; i < 8; ++i) {
        float4v v = p4[t + i * 256];
        for (int j = 0; j < 4; ++j) { sum += v[j]; sq += v[j] * v[j]; }
    }
    for (int off = 32; off; off >>= 1) {
        sum += __shfl_down(sum, off, 64);
        sq  += __shfl_down(sq,  off, 64);
    }
    __shared__ float ls[8];
    int wave = t >> 6, lane = t & 63;
    if (lane == 0) { ls[wave * 2] = sum; ls[wave * 2 + 1] = sq; }
    __syncthreads();
    if (t == 0) {
        float S = 0.f, Q = 0.f;
        for (int w = 0; w < 4; ++w) { S += ls[w * 2]; Q += ls[w * 2 + 1]; }
        int idx = (b * NGROUP + g) * 16 + s;
        psum[idx] = S; psq[idx] = Q;
    }
}

// ---------------- GroupNorm: finalize stats ----------------
__global__ void gn_stats(const float* __restrict__ psum, const float* __restrict__ psq,
                         float* __restrict__ stats) {
    int t = threadIdx.x;
    if (t < BATCH * NGROUP) {
        float S = 0.f, Q = 0.f;
        for (int s = 0; s < 16; ++s) { S += psum[t * 16 + s]; Q += psq[t * 16 + s]; }
        const float M = (float)(CPG * NTOK);
        float mean = S / M;
        float var  = Q / M - mean * mean;
        stats[t * 2]     = mean;
        stats[t * 2 + 1] = rsqrtf(var + EPSV);
    }
}

// ---------------- GroupNorm: normalize + transpose to hT[b][n][c] (bf16) ----------------
__global__ void gn_norm(const float* __restrict__ x, const float* __restrict__ nw,
                        const float* __restrict__ nb_, const float* __restrict__ stats,
                        unsigned short* __restrict__ hT) {
    int t = threadIdx.x;
    int n = blockIdx.x * 64 + (t & 63);
    int cb = blockIdx.y * 32 + (t >> 6) * 8;
    int b = blockIdx.z;
    short8 h8;
    for (int j = 0; j < 8; ++j) {
        int c = cb + j;
        int g = c >> 5;
        float mean = stats[(b * NGROUP + g) * 2];
        float inv  = stats[(b * NGROUP + g) * 2 + 1];
        float w  = nw[c] * inv;
        float bb = nb_[c] - mean * w;
        float v = x[((size_t)(b * CH + c)) * NTOK + n];
        h8[j] = (short)f2bf(v * w + bb);
    }
    *(short8*)(hT + ((size_t)b * NTOK + n) * CH + cb) = h8;
}

// ---------------- QKV GEMM (bf16 MFMA), scatter to qT/kT/v ----------------
__global__ __launch_bounds__(256) void qkv_gemm(const unsigned short* __restrict__ hT,
        const unsigned short* __restrict__ wq, const float* __restrict__ bq,
        unsigned short* __restrict__ qT, unsigned short* __restrict__ kT,
        unsigned short* __restrict__ vv) {
    int nb = blockIdx.x;       // 0..63 (n tile of 64)
    int ob = blockIdx.y;       // 0..11 (o tile of 64)
    int b  = blockIdx.z;
    int t = threadIdx.x;
    int wave = t >> 6, lane = t & 63;
    int l15 = lane & 15, quad = lane >> 4;
    int o0 = ob * 64 + wave * 16;

    short8 aW[8];
    {
        const unsigned short* wr = wq + (size_t)(o0 + l15) * CH + quad * 8;
        for (int kc = 0; kc < 8; ++kc) aW[kc] = *(const short8*)(wr + kc * 32);
    }
    float4v acc[4];
    for (int nt = 0; nt < 4; ++nt) for (int r = 0; r < 4; ++r) acc[nt][r] = 0.f;

    for (int kc = 0; kc < 8; ++kc) {
        for (int nt = 0; nt < 4; ++nt) {
            const short8* pb = (const short8*)(hT +
                ((size_t)b * NTOK + nb * 64 + nt * 16 + l15) * CH + kc * 32 + quad * 8);
            acc[nt] = __builtin_amdgcn_mfma_f32_16x16x32_bf16(aW[kc], *pb, acc[nt], 0, 0, 0);
        }
    }
    for (int nt = 0; nt < 4; ++nt) {
        int n = nb * 64 + nt * 16 + l15;
        for (int r = 0; r < 4; ++r) {
            int o = o0 + quad * 4 + r;
            float val = acc[nt][r] + bq[o];
            unsigned short bv = f2bf(val);
            int cch = o & 255;
            int seg = o >> 8;          // 0=q (pre-scaled), 1=k, 2=v
            int hh = cch >> 6, ci = cch & 63;
            if (seg == 0)      qT[(((size_t)b * NH + hh) * NTOK + n) * HD + ci] = bv;
            else if (seg == 1) kT[(((size_t)b * NH + hh) * NTOK + n) * HD + ci] = bv;
            else               vv[(((size_t)b * NH + hh) * HD + ci) * NTOK + n] = bv;
        }
    }
}

// ---------------- Flash attention: S^T trick (register P->PV), 128-key tiles, split x4 ----
// QK^T computed as S^T = K*Q^T (A=K, B=Q). C-layout of S^T: lane l15 = q-row,
// reg r = key (quad*4+r). That IS the A-fragment layout of mfma_16x16x16_bf16,
// so P feeds PV directly from registers -- no LDS round-trip.
__global__ __launch_bounds__(256, 4) void attn_kernel(const unsigned short* __restrict__ qT,
        const unsigned short* __restrict__ kT, const unsigned short* __restrict__ vv,
        unsigned short* __restrict__ opb, float* __restrict__ lpb) {
    int nb = blockIdx.x;          // 0..31 : 128 query rows per block
    int h  = blockIdx.y;
    int zb = blockIdx.z;          // 0..7 : (b, split)
    int sp = zb & 3, b = zb >> 2;
    int t = threadIdx.x, wave = t >> 6, lane = t & 63;
    int l15 = lane & 15, quad = lane >> 4;
    int n0 = nb * 128 + wave * 32;     // wave owns 2 m-tiles of 16 rows
    int kv0 = sp * (NTOK / NSPLIT);

    unsigned short* opart = opb + (size_t)sp * ((size_t)BATCH * NTOK * CH);
    float* lpart = lpb + (size_t)sp * (BATCH * NH * NTOK);

    const unsigned short* qbh = qT + ((size_t)(b * NH + h)) * NTOK * HD;
    const unsigned short* kbh = kT + ((size_t)(b * NH + h)) * NTOK * HD;
    const unsigned short* vbh = vv + ((size_t)(b * NH + h)) * HD * NTOK;

    // kbuf: 128 keys x 64 hd, stride 80 (b128 reads spread evenly over bank groups)
    // vbuf: 64 hd x 128 keys, stride 136
    __shared__ __align__(16) unsigned short kbuf[128 * 80];
    __shared__ __align__(16) unsigned short vbuf[64 * 136];

    short8 aQ[2][2];   // B-fragment of QK: B[q-row=l15][hd k=quad*8+j]
    for (int mt = 0; mt < 2; ++mt) {
        aQ[mt][0] = *(const short8*)(qbh + (size_t)(n0 + mt * 16 + l15) * HD + quad * 8);
        aQ[mt][1] = *(const short8*)(qbh + (size_t)(n0 + mt * 16 + l15) * HD + 32 + quad * 8);
    }

    float l_p[2] = {0.f, 0.f};         // per-lane partial denom (q-row = l15)
    float4v o_acc[2][4];
    for (int mt = 0; mt < 2; ++mt)
        for (int ct = 0; ct < 4; ++ct)
            for (int r = 0; r < 4; ++r) o_acc[mt][ct][r] = 0.f;

    for (int ms = kv0; ms < kv0 + NTOK / NSPLIT; ms += 128) {
        __syncthreads();   // previous iteration's reads done before overwrite
#pragma unroll
        for (int p = 0; p < 4; ++p) {
            int slot = p * 256 + t;
            int r = slot >> 3, c = slot & 7;
            short8 kd = *(const short8*)(kbh + (size_t)(ms + r) * HD + c * 8);
            *(short8*)(kbuf + r * 80 + c * 8) = kd;
        }
#pragma unroll
        for (int p = 0; p < 4; ++p) {
            int slot = p * 256 + t;
            int r = slot >> 4, c = slot & 15;
            short8 vd = *(const short8*)(vbh + (size_t)r * NTOK + ms + c * 8);
            *(short8*)(vbuf + r * 136 + c * 8) = vd;
        }
        __syncthreads();

#pragma unroll
        for (int kh = 0; kh < 2; ++kh) {      // two 64-key halves
            // S^T tiles: A = K-frag (lane = key row), B = Q-frag (lane = q row)
            float4v s[2][4];
#pragma unroll
            for (int nt = 0; nt < 4; ++nt) {
                int krow = kh * 64 + nt * 16 + l15;
                short8 ak0 = *(const short8*)(kbuf + krow * 80 + quad * 8);
                short8 ak1 = *(const short8*)(kbuf + krow * 80 + 32 + quad * 8);
#pragma unroll
                for (int mt = 0; mt < 2; ++mt) {
                    float4v z;
                    for (int r = 0; r < 4; ++r) z[r] = 0.f;
                    z = __builtin_amdgcn_mfma_f32_16x16x32_bf16(ak0, aQ[mt][0], z, 0, 0, 0);
                    z = __builtin_amdgcn_mfma_f32_16x16x32_bf16(ak1, aQ[mt][1], z, 0, 0, 0);
                    s[mt][nt] = z;
                }
            }
            // P = exp2(S^T), accumulate per-lane denom, pack to K16 A-fragments
            s4bf aP[2][4];
#pragma unroll
            for (int mt = 0; mt < 2; ++mt) {
#pragma unroll
                for (int nt = 0; nt < 4; ++nt) {
                    float e0 = __builtin_amdgcn_exp2f(s[mt][nt][0]);
                    float e1 = __builtin_amdgcn_exp2f(s[mt][nt][1]);
                    float e2 = __builtin_amdgcn_exp2f(s[mt][nt][2]);
                    float e3 = __builtin_amdgcn_exp2f(s[mt][nt][3]);
                    l_p[mt] += (e0 + e1) + (e2 + e3);
                    s4bf ap;
                    ap[0] = (short)f2bf_fast(e0);
                    ap[1] = (short)f2bf_fast(e1);
                    ap[2] = (short)f2bf_fast(e2);
                    ap[3] = (short)f2bf_fast(e3);
                    aP[mt][nt] = ap;
                }
            }
            // PV: B-frag = V^T chunk, 8B LDS loads, shared across m-tiles
#pragma unroll
            for (int ct = 0; ct < 4; ++ct) {
#pragma unroll
                for (int nt = 0; nt < 4; ++nt) {
                    s4bf bv = *(const s4bf*)(vbuf + (ct * 16 + l15) * 136 + kh * 64 + nt * 16 + quad * 4);
#pragma unroll
                    for (int mt = 0; mt < 2; ++mt)
                        o_acc[mt][ct] = __builtin_amdgcn_mfma_f32_16x16x16bf16_1k(aP[mt][nt], bv, o_acc[mt][ct], 0, 0, 0);
                }
            }
        }
    }
    // reduce denom over the 4 quads (key blocks); q-row = l15
    for (int mt = 0; mt < 2; ++mt) {
        l_p[mt] += __shfl_xor(l_p[mt], 16, 64);
        l_p[mt] += __shfl_xor(l_p[mt], 32, 64);
    }
    // store unnormalized partial O (bf16): C-layout col=l15=d, row=quad*4+r=q-row
    for (int mt = 0; mt < 2; ++mt) {
        for (int ct = 0; ct < 4; ++ct) {
            for (int r = 0; r < 4; ++r) {
                int n = n0 + mt * 16 + quad * 4 + r;
                int cg = h * HD + ct * 16 + l15;
                opart[((size_t)b * NTOK + n) * CH + cg] = f2bf(o_acc[mt][ct][r]);
            }
        }
        if (lane < 16)
            lpart[((size_t)(b * NH + h)) * NTOK + n0 + mt * 16 + lane] = l_p[mt];
    }
}

// ---------------- combine split-KV partials (4 splits) ----------------
__global__ void attn_combine(const unsigned short* __restrict__ opb,
                             const float* __restrict__ lpb,
                             unsigned short* __restrict__ oT) {
    int idx = blockIdx.x * 256 + threadIdx.x;   // chunk of 8 channels
    int c0 = (idx & 31) * 8;
    int n  = (idx >> 5) & (NTOK - 1);
    int b  = idx >> 17;
    int h  = c0 >> 6;
    const size_t OP = (size_t)BATCH * NTOK * CH;
    const size_t LP = BATCH * NH * NTOK;
    size_t lidx = ((size_t)(b * NH + h)) * NTOK + n;
    float ls = lpb[lidx] + lpb[LP + lidx] + lpb[2 * LP + lidx] + lpb[3 * LP + lidx];
    float rinv = 1.0f / ls;
    size_t base = ((size_t)b * NTOK + n) * CH + c0;
    short8 o0 = *(const short8*)(opb + base);
    short8 o1 = *(const short8*)(opb + OP + base);
    short8 o2 = *(const short8*)(opb + 2 * OP + base);
    short8 o3 = *(const short8*)(opb + 3 * OP + base);
    short8 out;
    for (int j = 0; j < 8; ++j) {
        float f = (bf2f((unsigned short)o0[j]) + bf2f((unsigned short)o1[j]))
                + (bf2f((unsigned short)o2[j]) + bf2f((unsigned short)o3[j]));
        out[j] = (short)f2bf(f * rinv);
    }
    *(short8*)(oT + base) = out;
}

// ---------------- Proj GEMM + bias + residual ----------------
__global__ __launch_bounds__(256) void proj_gemm(const unsigned short* __restrict__ oT,
        const unsigned short* __restrict__ wp, const float* __restrict__ proj_b,
        const float* __restrict__ x, float* __restrict__ out) {
    int nb = blockIdx.x;   // 0..63
    int cb = blockIdx.y;   // 0..3
    int b  = blockIdx.z;
    int t = threadIdx.x, wave = t >> 6, lane = t & 63;
    int l15 = lane & 15, quad = lane >> 4;
    int c0 = cb * 64 + wave * 16;

    short8 aW[8];
    {
        const unsigned short* wr = wp + (size_t)(c0 + l15) * CH + quad * 8;
        for (int kc = 0; kc < 8; ++kc) aW[kc] = *(const short8*)(wr + kc * 32);
    }
    float4v acc[4];
    for (int nt = 0; nt < 4; ++nt) for (int r = 0; r < 4; ++r) acc[nt][r] = 0.f;

    for (int kc = 0; kc < 8; ++kc) {
        for (int nt = 0; nt < 4; ++nt) {
            const short8* pb = (const short8*)(oT +
                ((size_t)b * NTOK + nb * 64 + nt * 16 + l15) * CH + kc * 32 + quad * 8);
            acc[nt] = __builtin_amdgcn_mfma_f32_16x16x32_bf16(aW[kc], *pb, acc[nt], 0, 0, 0);
        }
    }
    for (int nt = 0; nt < 4; ++nt) {
        int n = nb * 64 + nt * 16 + l15;
        for (int r = 0; r < 4; ++r) {
            int cc = c0 + quad * 4 + r;
            size_t idx = ((size_t)(b * CH + cc)) * NTOK + n;
            out[idx] = acc[nt][r] + proj_b[cc] + x[idx];
        }
    }
}

extern "C" void kernel_launch(void* const* d_in, const int* in_sizes, int n_in,
                              void* d_out, int out_size, void* d_ws, size_t ws_size,
                              hipStream_t stream) {
    const float* x      = (const float*)d_in[0];
    const float* norm_w = (const float*)d_in[1];
    const float* norm_b = (const float*)d_in[2];
    const float* qkv_w  = (const float*)d_in[3];
    const float* qkv_b  = (const float*)d_in[4];
    const float* proj_w = (const float*)d_in[5];
    const float* proj_b = (const float*)d_in[6];
    float* out = (float*)d_out;

    char* ws = (char*)d_ws;
    float* psum  = (float*)ws;                       // 256 f
    float* psq   = (float*)(ws + 1024);              // 256 f
    float* stats = (float*)(ws + 2048);              // 32 f
    float* bqs   = (float*)(ws + 4096);              // 768 f
    unsigned short* wqb = (unsigned short*)(ws + 8192);        // 3*256*256 bf16 -> 401408
    unsigned short* wpb = (unsigned short*)(ws + 401408);      // 256*256 bf16   -> 532480
    float* lpb = (float*)(ws + 532480);              // 4 * 2*4*4096 f = 512 KB -> 1056768
    const size_t MB4 = 4194304;
    unsigned short* hT  = (unsigned short*)(ws + 2097152);     // 4 MB (aliases op slot 0)
    unsigned short* opb = hT;                                  // 4 x 4 MB partials -> ends 18 MB+2
    unsigned short* qT = (unsigned short*)(ws + 2097152 + 4 * MB4);
    unsigned short* kT = (unsigned short*)(ws + 2097152 + 5 * MB4);
    unsigned short* vv = (unsigned short*)(ws + 2097152 + 6 * MB4);
    unsigned short* oT = (unsigned short*)(ws + 2097152 + 7 * MB4);

    wcvt<<<dim3(256), dim3(256), 0, stream>>>(qkv_w, qkv_b, proj_w, wqb, bqs, wpb);
    gn_partial<<<dim3(16, NGROUP, BATCH), dim3(256), 0, stream>>>(x, psum, psq);
    gn_stats<<<dim3(1), dim3(64), 0, stream>>>(psum, psq, stats);
    gn_norm<<<dim3(64, 8, BATCH), dim3(256), 0, stream>>>(x, norm_w, norm_b, stats, hT);
    qkv_gemm<<<dim3(64, 12, BATCH), dim3(256), 0, stream>>>(hT, wqb, bqs, qT, kT, vv);
    attn_kernel<<<dim3(32, NH, BATCH * NSPLIT), dim3(256), 0, stream>>>(qT, kT, vv, opb, lpb);
    attn_combine<<<dim3(1024), dim3(256), 0, stream>>>(opb, lpb, oT);
    proj_gemm<<<dim3(64, 4, BATCH), dim3(256), 0, stream>>>(oT, wpb, proj_b, x, out);
}

// Round 6
// 176.575 us; speedup vs baseline: 2.0980x; 1.0293x over previous
//
#include <hip/hip_runtime.h>
#include <hip/hip_bf16.h>

#define BATCH 2
#define CH 256
#define NH 4
#define HD 64
#define NGROUP 8
#define CPG 32
#define NTOK 4096
#define EPSV 1e-5f
// scale = hd^-0.5 = 0.125, folded with log2(e) so P = exp2(q'.k)
#define QSCALE 0.1803368801111204f
#define NSPLIT 4

typedef __attribute__((ext_vector_type(8))) short short8;
typedef __attribute__((ext_vector_type(4))) short s4bf;
typedef __attribute__((ext_vector_type(4))) float float4v;
typedef __attribute__((ext_vector_type(16))) float f16v;

__device__ __forceinline__ unsigned short f2bf(float f) {
    union { float f; unsigned u; } v; v.f = f;
    unsigned r = v.u + 0x7FFF + ((v.u >> 16) & 1);
    return (unsigned short)(r >> 16);
}
__device__ __forceinline__ unsigned short f2bf_fast(float f) {
    union { float f; unsigned u; } v; v.f = f;
    return (unsigned short)((v.u + 0x8000u) >> 16);
}
__device__ __forceinline__ float bf2f(unsigned short u) {
    union { unsigned u; float f; } v; v.u = ((unsigned)u) << 16;
    return v.f;
}
// pack two f32 -> one VGPR of two bf16
__device__ __forceinline__ unsigned pk2bf(float a, float b) {
#if __has_builtin(__builtin_amdgcn_cvt_pk_bf16_f32)
    typedef __attribute__((ext_vector_type(2))) __bf16 bf2v;
    bf2v p = __builtin_amdgcn_cvt_pk_bf16_f32(a, b);
    union { bf2v v; unsigned u; } c; c.v = p;
    return c.u;
#else
    return (unsigned)f2bf_fast(a) | ((unsigned)f2bf_fast(b) << 16);
#endif
}

// ---------------- weight convert: f32 -> bf16 (q part pre-scaled) ----------------
__global__ void wcvt(const float* __restrict__ qkv_w, const float* __restrict__ qkv_b,
                     const float* __restrict__ proj_w,
                     unsigned short* __restrict__ wq, float* __restrict__ bq,
                     unsigned short* __restrict__ wp) {
    int idx = blockIdx.x * 256 + threadIdx.x;
    int stride = gridDim.x * 256;
    for (int i = idx; i < 3 * CH * CH; i += stride) {
        float f = qkv_w[i];
        if (i < CH * CH) f *= QSCALE;
        wq[i] = f2bf(f);
    }
    for (int i = idx; i < CH * CH; i += stride) wp[i] = f2bf(proj_w[i]);
    for (int i = idx; i < 3 * CH; i += stride) {
        float f = qkv_b[i];
        if (i < CH) f *= QSCALE;
        bq[i] = f;
    }
}

// ---------------- GroupNorm: partial sums ----------------
__global__ void gn_partial(const float* __restrict__ x, float* __restrict__ psum,
                           float* __restrict__ psq) {
    int s = blockIdx.x;   // 16 slices
    int g = blockIdx.y;   // 8 groups
    int b = blockIdx.z;   // 2 batches
    const float* base = x + ((size_t)(b * CH + g * CPG)) * NTOK + (size_t)s * 8192;
    int t = threadIdx.x;
    float sum = 0.f, sq = 0.f;
    const float4v* p4 = (const float4v*)base;
    for (int i = 0; i < 8; ++i) {
        float4v v = p4[t + i * 256];
        for (int j = 0; j < 4; ++j) { sum += v[j]; sq += v[j] * v[j]; }
    }
    for (int off = 32; off; off >>= 1) {
        sum += __shfl_down(sum, off, 64);
        sq  += __shfl_down(sq,  off, 64);
    }
    __shared__ float ls[8];
    int wave = t >> 6, lane = t & 63;
    if (lane == 0) { ls[wave * 2] = sum; ls[wave * 2 + 1] = sq; }
    __syncthreads();
    if (t == 0) {
        float S = 0.f, Q = 0.f;
        for (int w = 0; w < 4; ++w) { S += ls[w * 2]; Q += ls[w * 2 + 1]; }
        int idx = (b * NGROUP + g) * 16 + s;
        psum[idx] = S; psq[idx] = Q;
    }
}

// ---------------- GroupNorm: normalize + transpose (stats folded in) ----------------
__global__ void gn_norm(const float* __restrict__ x, const float* __restrict__ nw,
                        const float* __restrict__ nb_, const float* __restrict__ psum,
                        const float* __restrict__ psq, unsigned short* __restrict__ hT) {
    int t = threadIdx.x;
    int n = blockIdx.x * 64 + (t & 63);
    int g = blockIdx.y;                    // block covers exactly one group (32 ch)
    int cb = g * 32 + (t >> 6) * 8;
    int b = blockIdx.z;
    float S = 0.f, Q = 0.f;
    for (int s = 0; s < 16; ++s) {
        S += psum[(b * NGROUP + g) * 16 + s];
        Q += psq[(b * NGROUP + g) * 16 + s];
    }
    const float M = (float)(CPG * NTOK);
    float mean = S / M;
    float inv  = rsqrtf(Q / M - mean * mean + EPSV);
    short8 h8;
    for (int j = 0; j < 8; ++j) {
        int c = cb + j;
        float w  = nw[c] * inv;
        float bb = nb_[c] - mean * w;
        float v = x[((size_t)(b * CH + c)) * NTOK + n];
        h8[j] = (short)f2bf(v * w + bb);
    }
    *(short8*)(hT + ((size_t)b * NTOK + n) * CH + cb) = h8;
}

// ---------------- QKV GEMM (bf16 MFMA, LDS-staged B), scatter to qT/kT/v ----------------
__global__ __launch_bounds__(256) void qkv_gemm(const unsigned short* __restrict__ hT,
        const unsigned short* __restrict__ wq, const float* __restrict__ bq,
        unsigned short* __restrict__ qT, unsigned short* __restrict__ kT,
        unsigned short* __restrict__ vv) {
    int nb = blockIdx.x;       // 0..63 (n tile of 64)
    int ob = blockIdx.y;       // 0..11 (o tile of 64)
    int b  = blockIdx.z;
    int t = threadIdx.x;
    int wave = t >> 6, lane = t & 63;
    int l15 = lane & 15, quad = lane >> 4;
    int o0 = ob * 64 + wave * 16;

    __shared__ __align__(16) unsigned short bt[64 * 264];   // 132 dw stride (==4 mod 32)

    short8 aW[8];
    {
        const unsigned short* wr = wq + (size_t)(o0 + l15) * CH + quad * 8;
        for (int kc = 0; kc < 8; ++kc) aW[kc] = *(const short8*)(wr + kc * 32);
    }
    // stage B tile: 64 n-rows x 256 c
    for (int p = 0; p < 8; ++p) {
        int slot = p * 256 + t;
        int r = slot >> 5, c = slot & 31;
        *(short8*)(bt + r * 264 + c * 8) =
            *(const short8*)(hT + ((size_t)b * NTOK + nb * 64 + r) * CH + c * 8);
    }
    __syncthreads();

    float4v acc[4];
    for (int nt = 0; nt < 4; ++nt) for (int r = 0; r < 4; ++r) acc[nt][r] = 0.f;
    for (int kc = 0; kc < 8; ++kc) {
        for (int nt = 0; nt < 4; ++nt) {
            short8 pb = *(const short8*)(bt + (nt * 16 + l15) * 264 + kc * 32 + quad * 8);
            acc[nt] = __builtin_amdgcn_mfma_f32_16x16x32_bf16(aW[kc], pb, acc[nt], 0, 0, 0);
        }
    }
    for (int nt = 0; nt < 4; ++nt) {
        int n = nb * 64 + nt * 16 + l15;
        for (int r = 0; r < 4; ++r) {
            int o = o0 + quad * 4 + r;
            float val = acc[nt][r] + bq[o];
            unsigned short bv = f2bf(val);
            int cch = o & 255;
            int seg = o >> 8;          // 0=q (pre-scaled), 1=k, 2=v
            int hh = cch >> 6, ci = cch & 63;
            if (seg == 0)      qT[(((size_t)b * NH + hh) * NTOK + n) * HD + ci] = bv;
            else if (seg == 1) kT[(((size_t)b * NH + hh) * NTOK + n) * HD + ci] = bv;
            else               vv[(((size_t)b * NH + hh) * HD + ci) * NTOK + n] = bv;
        }
    }
}

// ---------------- Flash attention: 32x32 MFMA path, register P->PV, split x4 ----------
// S^T = K*Q^T via mfma_32x32x16 (A=K, B=Q). C regs 4f..4f+3 of the 32x32 tile are
// exactly the A-fragment of mfma_32x32x8bf16_1k for key-block f (k=4*half+j).
__global__ __launch_bounds__(256, 2) void attn_kernel(const unsigned short* __restrict__ qT,
        const unsigned short* __restrict__ kT, const unsigned short* __restrict__ vv,
        unsigned short* __restrict__ opb, float* __restrict__ lpb) {
    int nb = blockIdx.x;          // 0..15 : 256 q-rows per block
    int h  = blockIdx.y;
    int zb = blockIdx.z;          // (b, split)
    int sp = zb & 3, b = zb >> 2;
    int t = threadIdx.x, wave = t >> 6, lane = t & 63;
    int l31 = lane & 31, half = lane >> 5;
    int n0 = nb * 256 + wave * 64;     // wave owns 2 q-blocks of 32 rows
    int kv0 = sp * (NTOK / NSPLIT);

    unsigned short* opart = opb + (size_t)sp * ((size_t)BATCH * NTOK * CH);
    float* lpart = lpb + (size_t)sp * (BATCH * NH * NTOK);

    const unsigned short* qbh = qT + ((size_t)(b * NH + h)) * NTOK * HD;
    const unsigned short* kbh = kT + ((size_t)(b * NH + h)) * NTOK * HD;
    const unsigned short* vbh = vv + ((size_t)(b * NH + h)) * HD * NTOK;

    // kbuf [key][hd] stride 72 shorts (36 dw == 4 mod 32); vbuf [d][key] stride 136 (68 dw)
    __shared__ __align__(16) unsigned short kbuf[128 * 72];
    __shared__ __align__(16) unsigned short vbuf[64 * 136];

    // Q B-fragments: B[n=q=l31][k=16*kc + 8*half + j]
    short8 aQ[2][4];
    for (int qb = 0; qb < 2; ++qb)
        for (int kc = 0; kc < 4; ++kc)
            aQ[qb][kc] = *(const short8*)(qbh + (size_t)(n0 + qb * 32 + l31) * HD + kc * 16 + half * 8);

    float l_p[2] = {0.f, 0.f};
    f16v o_acc[2][2];
    for (int qb = 0; qb < 2; ++qb)
        for (int ct = 0; ct < 2; ++ct)
            for (int r = 0; r < 16; ++r) o_acc[qb][ct][r] = 0.f;

    for (int ms = kv0; ms < kv0 + NTOK / NSPLIT; ms += 128) {
        __syncthreads();
#pragma unroll
        for (int p = 0; p < 4; ++p) {        // K tile: 128 keys x 64 hd
            int slot = p * 256 + t;
            int r = slot >> 3, c = slot & 7;
            *(short8*)(kbuf + r * 72 + c * 8) =
                *(const short8*)(kbh + (size_t)(ms + r) * HD + c * 8);
        }
#pragma unroll
        for (int p = 0; p < 4; ++p) {        // V tile: 64 d x 128 keys
            int slot = p * 256 + t;
            int r = slot >> 4, c = slot & 15;
            *(short8*)(vbuf + r * 136 + c * 8) =
                *(const short8*)(vbh + (size_t)r * NTOK + ms + c * 8);
        }
        __syncthreads();

#pragma unroll
        for (int kb = 0; kb < 4; ++kb) {     // 32-key blocks
            short8 ak[4];
#pragma unroll
            for (int kc = 0; kc < 4; ++kc)
                ak[kc] = *(const short8*)(kbuf + (kb * 32 + l31) * 72 + kc * 16 + half * 8);
            s4bf aP[2][4];
#pragma unroll
            for (int qb = 0; qb < 2; ++qb) {
                f16v S;
                for (int r = 0; r < 16; ++r) S[r] = 0.f;
#pragma unroll
                for (int kc = 0; kc < 4; ++kc)
                    S = __builtin_amdgcn_mfma_f32_32x32x16_bf16(ak[kc], aQ[qb][kc], S, 0, 0, 0);
                float e[16];
#pragma unroll
                for (int r = 0; r < 16; ++r) e[r] = __builtin_amdgcn_exp2f(S[r]);
                float s0 = ((e[0] + e[1]) + (e[2] + e[3])) + ((e[4] + e[5]) + (e[6] + e[7]));
                float s1 = ((e[8] + e[9]) + (e[10] + e[11])) + ((e[12] + e[13]) + (e[14] + e[15]));
                l_p[qb] += s0 + s1;
#pragma unroll
                for (int f = 0; f < 4; ++f) {
                    s4bf ap;
                    union { s4bf v; unsigned u[2]; } c;
                    c.u[0] = pk2bf(e[4 * f], e[4 * f + 1]);
                    c.u[1] = pk2bf(e[4 * f + 2], e[4 * f + 3]);
                    aP[qb][f] = c.v;
                }
            }
#pragma unroll
            for (int ct = 0; ct < 2; ++ct) {
#pragma unroll
                for (int f = 0; f < 4; ++f) {
                    s4bf bv = *(const s4bf*)(vbuf + (ct * 32 + l31) * 136 + kb * 32 + f * 8 + half * 4);
#pragma unroll
                    for (int qb = 0; qb < 2; ++qb)
                        o_acc[qb][ct] = __builtin_amdgcn_mfma_f32_32x32x8bf16_1k(aP[qb][f], bv, o_acc[qb][ct], 0, 0, 0);
                }
            }
        }
    }
    // lanes l and l+32 hold complementary key halves of the same q-row
    for (int qb = 0; qb < 2; ++qb)
        l_p[qb] += __shfl_xor(l_p[qb], 32, 64);
    // store: O C-layout col=l31=d, row r -> q = (r&3)+8*(r>>2)+4*half
    for (int qb = 0; qb < 2; ++qb) {
        for (int ct = 0; ct < 2; ++ct) {
#pragma unroll
            for (int r = 0; r < 16; ++r) {
                int q = n0 + qb * 32 + (r & 3) + 8 * (r >> 2) + 4 * half;
                int cg = h * HD + ct * 32 + l31;
                opart[((size_t)b * NTOK + q) * CH + cg] = f2bf(o_acc[qb][ct][r]);
            }
        }
        if (lane < 32)
            lpart[((size_t)(b * NH + h)) * NTOK + n0 + qb * 32 + lane] = l_p[qb];
    }
}

// ---------------- combine split-KV partials (4 splits) ----------------
__global__ void attn_combine(const unsigned short* __restrict__ opb,
                             const float* __restrict__ lpb,
                             unsigned short* __restrict__ oT) {
    int idx = blockIdx.x * 256 + threadIdx.x;   // chunk of 8 channels
    int c0 = (idx & 31) * 8;
    int n  = (idx >> 5) & (NTOK - 1);
    int b  = idx >> 17;
    int h  = c0 >> 6;
    const size_t OP = (size_t)BATCH * NTOK * CH;
    const size_t LP = BATCH * NH * NTOK;
    size_t lidx = ((size_t)(b * NH + h)) * NTOK + n;
    float ls = lpb[lidx] + lpb[LP + lidx] + lpb[2 * LP + lidx] + lpb[3 * LP + lidx];
    float rinv = 1.0f / ls;
    size_t base = ((size_t)b * NTOK + n) * CH + c0;
    short8 o0 = *(const short8*)(opb + base);
    short8 o1 = *(const short8*)(opb + OP + base);
    short8 o2 = *(const short8*)(opb + 2 * OP + base);
    short8 o3 = *(const short8*)(opb + 3 * OP + base);
    short8 out;
    for (int j = 0; j < 8; ++j) {
        float f = (bf2f((unsigned short)o0[j]) + bf2f((unsigned short)o1[j]))
                + (bf2f((unsigned short)o2[j]) + bf2f((unsigned short)o3[j]));
        out[j] = (short)f2bf(f * rinv);
    }
    *(short8*)(oT + base) = out;
}

// ---------------- Proj GEMM (LDS-staged B) + bias + residual ----------------
__global__ __launch_bounds__(256) void proj_gemm(const unsigned short* __restrict__ oT,
        const unsigned short* __restrict__ wp, const float* __restrict__ proj_b,
        const float* __restrict__ x, float* __restrict__ out) {
    int nb = blockIdx.x;   // 0..63
    int cb = blockIdx.y;   // 0..3
    int b  = blockIdx.z;
    int t = threadIdx.x, wave = t >> 6, lane = t & 63;
    int l15 = lane & 15, quad = lane >> 4;
    int c0 = cb * 64 + wave * 16;

    __shared__ __align__(16) unsigned short bt[64 * 264];

    short8 aW[8];
    {
        const unsigned short* wr = wp + (size_t)(c0 + l15) * CH + quad * 8;
        for (int kc = 0; kc < 8; ++kc) aW[kc] = *(const short8*)(wr + kc * 32);
    }
    for (int p = 0; p < 8; ++p) {
        int slot = p * 256 + t;
        int r = slot >> 5, c = slot & 31;
        *(short8*)(bt + r * 264 + c * 8) =
            *(const short8*)(oT + ((size_t)b * NTOK + nb * 64 + r) * CH + c * 8);
    }
    __syncthreads();

    float4v acc[4];
    for (int nt = 0; nt < 4; ++nt) for (int r = 0; r < 4; ++r) acc[nt][r] = 0.f;
    for (int kc = 0; kc < 8; ++kc) {
        for (int nt = 0; nt < 4; ++nt) {
            short8 pb = *(const short8*)(bt + (nt * 16 + l15) * 264 + kc * 32 + quad * 8);
            acc[nt] = __builtin_amdgcn_mfma_f32_16x16x32_bf16(aW[kc], pb, acc[nt], 0, 0, 0);
        }
    }
    for (int nt = 0; nt < 4; ++nt) {
        int n = nb * 64 + nt * 16 + l15;
        for (int r = 0; r < 4; ++r) {
            int cc = c0 + quad * 4 + r;
            size_t idx = ((size_t)(b * CH + cc)) * NTOK + n;
            out[idx] = acc[nt][r] + proj_b[cc] + x[idx];
        }
    }
}

extern "C" void kernel_launch(void* const* d_in, const int* in_sizes, int n_in,
                              void* d_out, int out_size, void* d_ws, size_t ws_size,
                              hipStream_t stream) {
    const float* x      = (const float*)d_in[0];
    const float* norm_w = (const float*)d_in[1];
    const float* norm_b = (const float*)d_in[2];
    const float* qkv_w  = (const float*)d_in[3];
    const float* qkv_b  = (const float*)d_in[4];
    const float* proj_w = (const float*)d_in[5];
    const float* proj_b = (const float*)d_in[6];
    float* out = (float*)d_out;

    char* ws = (char*)d_ws;
    float* psum  = (float*)ws;                       // 256 f
    float* psq   = (float*)(ws + 1024);              // 256 f
    float* bqs   = (float*)(ws + 4096);              // 768 f
    unsigned short* wqb = (unsigned short*)(ws + 8192);        // 3*256*256 bf16 -> 401408
    unsigned short* wpb = (unsigned short*)(ws + 401408);      // 256*256 bf16   -> 532480
    float* lpb = (float*)(ws + 532480);              // 4 * 2*4*4096 f = 512 KB
    const size_t MB4 = 4194304;
    unsigned short* hT  = (unsigned short*)(ws + 2097152);     // 4 MB (aliases op slot 0)
    unsigned short* opb = hT;                                  // 4 x 4 MB partials
    unsigned short* qT = (unsigned short*)(ws + 2097152 + 4 * MB4);
    unsigned short* kT = (unsigned short*)(ws + 2097152 + 5 * MB4);
    unsigned short* vv = (unsigned short*)(ws + 2097152 + 6 * MB4);
    unsigned short* oT = (unsigned short*)(ws + 2097152 + 7 * MB4);

    wcvt<<<dim3(256), dim3(256), 0, stream>>>(qkv_w, qkv_b, proj_w, wqb, bqs, wpb);
    gn_partial<<<dim3(16, NGROUP, BATCH), dim3(256), 0, stream>>>(x, psum, psq);
    gn_norm<<<dim3(64, 8, BATCH), dim3(256), 0, stream>>>(x, norm_w, norm_b, psum, psq, hT);
    qkv_gemm<<<dim3(64, 12, BATCH), dim3(256), 0, stream>>>(hT, wqb, bqs, qT, kT, vv);
    attn_kernel<<<dim3(16, NH, BATCH * NSPLIT), dim3(256), 0, stream>>>(qT, kT, vv, opb, lpb);
    attn_combine<<<dim3(1024), dim3(256), 0, stream>>>(opb, lpb, oT);
    proj_gemm<<<dim3(64, 4, BATCH), dim3(256), 0, stream>>>(oT, wpb, proj_b, x, out);
}

// Round 7
// 154.638 us; speedup vs baseline: 2.3957x; 1.1419x over previous
//
#include <hip/hip_runtime.h>
#include <hip/hip_bf16.h>

#define BATCH 2
#define CH 256
#define NH 4
#define HD 64
#define NGROUP 8
#define CPG 32
#define NTOK 4096
#define EPSV 1e-5f
// scale = hd^-0.5 = 0.125, folded with log2(e) so P = exp2(q'.k)
#define QSCALE 0.1803368801111204f
#define NSPLIT 4

typedef __attribute__((ext_vector_type(8))) short short8;
typedef __attribute__((ext_vector_type(4))) short s4bf;
typedef __attribute__((ext_vector_type(4))) float float4v;

__device__ __forceinline__ unsigned short f2bf(float f) {
    union { float f; unsigned u; } v; v.f = f;
    unsigned r = v.u + 0x7FFF + ((v.u >> 16) & 1);
    return (unsigned short)(r >> 16);
}
__device__ __forceinline__ unsigned short f2bf_fast(float f) {
    union { float f; unsigned u; } v; v.f = f;
    return (unsigned short)((v.u + 0x8000u) >> 16);
}
__device__ __forceinline__ float bf2f(unsigned short u) {
    union { unsigned u; float f; } v; v.u = ((unsigned)u) << 16;
    return v.f;
}
// pack two f32 -> one VGPR holding two bf16
__device__ __forceinline__ unsigned pk2bf(float a, float b) {
#if __has_builtin(__builtin_amdgcn_cvt_pk_bf16_f32)
    typedef __attribute__((ext_vector_type(2))) __bf16 bf2v;
    bf2v p = __builtin_amdgcn_cvt_pk_bf16_f32(a, b);
    union { bf2v v; unsigned u; } c; c.v = p;
    return c.u;
#else
    return (unsigned)f2bf_fast(a) | ((unsigned)f2bf_fast(b) << 16);
#endif
}

// ---------------- prep: fused wcvt + gn_partial (independent work) ----------------
__global__ void prep(const float* __restrict__ x,
                     const float* __restrict__ qkv_w, const float* __restrict__ qkv_b,
                     const float* __restrict__ proj_w,
                     float* __restrict__ psum, float* __restrict__ psq,
                     unsigned short* __restrict__ wq, float* __restrict__ bq,
                     unsigned short* __restrict__ wp) {
    int bx = blockIdx.x;
    int t = threadIdx.x;
    if (bx < 256) {
        // -------- gn_partial --------
        int s = bx & 15, g = (bx >> 4) & 7, b = bx >> 7;
        const float* base = x + ((size_t)(b * CH + g * CPG)) * NTOK + (size_t)s * 8192;
        float sum = 0.f, sq = 0.f;
        const float4v* p4 = (const float4v*)base;
        for (int i = 0; i < 8; ++i) {
            float4v v = p4[t + i * 256];
            for (int j = 0; j < 4; ++j) { sum += v[j]; sq += v[j] * v[j]; }
        }
        for (int off = 32; off; off >>= 1) {
            sum += __shfl_down(sum, off, 64);
            sq  += __shfl_down(sq,  off, 64);
        }
        __shared__ float ls[8];
        int wave = t >> 6, lane = t & 63;
        if (lane == 0) { ls[wave * 2] = sum; ls[wave * 2 + 1] = sq; }
        __syncthreads();
        if (t == 0) {
            float S = 0.f, Q = 0.f;
            for (int w = 0; w < 4; ++w) { S += ls[w * 2]; Q += ls[w * 2 + 1]; }
            int idx = (b * NGROUP + g) * 16 + s;
            psum[idx] = S; psq[idx] = Q;
        }
    } else {
        // -------- wcvt --------
        int idx = (bx - 256) * 256 + t;
        int stride = 256 * 256;
        for (int i = idx; i < 3 * CH * CH; i += stride) {
            float f = qkv_w[i];
            if (i < CH * CH) f *= QSCALE;
            wq[i] = f2bf(f);
        }
        for (int i = idx; i < CH * CH; i += stride) wp[i] = f2bf(proj_w[i]);
        for (int i = idx; i < 3 * CH; i += stride) {
            float f = qkv_b[i];
            if (i < CH) f *= QSCALE;
            bq[i] = f;
        }
    }
}

// ---------------- GroupNorm: normalize + transpose (stats folded in) ----------------
__global__ void gn_norm(const float* __restrict__ x, const float* __restrict__ nw,
                        const float* __restrict__ nb_, const float* __restrict__ psum,
                        const float* __restrict__ psq, unsigned short* __restrict__ hT) {
    int t = threadIdx.x;
    int n = blockIdx.x * 64 + (t & 63);
    int g = blockIdx.y;                    // block covers exactly one group (32 ch)
    int cb = g * 32 + (t >> 6) * 8;
    int b = blockIdx.z;
    float S = 0.f, Q = 0.f;
    for (int s = 0; s < 16; ++s) {
        S += psum[(b * NGROUP + g) * 16 + s];
        Q += psq[(b * NGROUP + g) * 16 + s];
    }
    const float M = (float)(CPG * NTOK);
    float mean = S / M;
    float inv  = rsqrtf(Q / M - mean * mean + EPSV);
    short8 h8;
    for (int j = 0; j < 8; ++j) {
        int c = cb + j;
        float w  = nw[c] * inv;
        float bb = nb_[c] - mean * w;
        float v = x[((size_t)(b * CH + c)) * NTOK + n];
        h8[j] = (short)f2bf(v * w + bb);
    }
    *(short8*)(hT + ((size_t)b * NTOK + n) * CH + cb) = h8;
}

// ---------------- QKV GEMM (bf16 MFMA, LDS-staged B), scatter to qT/kT/v ----------------
__global__ __launch_bounds__(256) void qkv_gemm(const unsigned short* __restrict__ hT,
        const unsigned short* __restrict__ wq, const float* __restrict__ bq,
        unsigned short* __restrict__ qT, unsigned short* __restrict__ kT,
        unsigned short* __restrict__ vv) {
    int nb = blockIdx.x;       // 0..63 (n tile of 64)
    int ob = blockIdx.y;       // 0..11 (o tile of 64)
    int b  = blockIdx.z;
    int t = threadIdx.x;
    int wave = t >> 6, lane = t & 63;
    int l15 = lane & 15, quad = lane >> 4;
    int o0 = ob * 64 + wave * 16;

    __shared__ __align__(16) unsigned short bt[64 * 264];   // 132 dw stride (==4 mod 32)

    short8 aW[8];
    {
        const unsigned short* wr = wq + (size_t)(o0 + l15) * CH + quad * 8;
        for (int kc = 0; kc < 8; ++kc) aW[kc] = *(const short8*)(wr + kc * 32);
    }
    // stage B tile: 64 n-rows x 256 c
    for (int p = 0; p < 8; ++p) {
        int slot = p * 256 + t;
        int r = slot >> 5, c = slot & 31;
        *(short8*)(bt + r * 264 + c * 8) =
            *(const short8*)(hT + ((size_t)b * NTOK + nb * 64 + r) * CH + c * 8);
    }
    __syncthreads();

    float4v acc[4];
    for (int nt = 0; nt < 4; ++nt) for (int r = 0; r < 4; ++r) acc[nt][r] = 0.f;
    for (int kc = 0; kc < 8; ++kc) {
        for (int nt = 0; nt < 4; ++nt) {
            short8 pb = *(const short8*)(bt + (nt * 16 + l15) * 264 + kc * 32 + quad * 8);
            acc[nt] = __builtin_amdgcn_mfma_f32_16x16x32_bf16(aW[kc], pb, acc[nt], 0, 0, 0);
        }
    }
    for (int nt = 0; nt < 4; ++nt) {
        int n = nb * 64 + nt * 16 + l15;
        for (int r = 0; r < 4; ++r) {
            int o = o0 + quad * 4 + r;
            float val = acc[nt][r] + bq[o];
            unsigned short bv = f2bf(val);
            int cch = o & 255;
            int seg = o >> 8;          // 0=q (pre-scaled), 1=k, 2=v
            int hh = cch >> 6, ci = cch & 63;
            if (seg == 0)      qT[(((size_t)b * NH + hh) * NTOK + n) * HD + ci] = bv;
            else if (seg == 1) kT[(((size_t)b * NH + hh) * NTOK + n) * HD + ci] = bv;
            else               vv[(((size_t)b * NH + hh) * HD + ci) * NTOK + n] = bv;
        }
    }
}

// ---------------- Flash attention: S^T trick (register P->PV), 128-key tiles, split x4 ----
// (round-5 verified structure; P packing via v_cvt_pk_bf16_f32)
__global__ __launch_bounds__(256, 4) void attn_kernel(const unsigned short* __restrict__ qT,
        const unsigned short* __restrict__ kT, const unsigned short* __restrict__ vv,
        unsigned short* __restrict__ opb, float* __restrict__ lpb) {
    int nb = blockIdx.x;          // 0..31 : 128 query rows per block
    int h  = blockIdx.y;
    int zb = blockIdx.z;          // (b, split)
    int sp = zb & 3, b = zb >> 2;
    int t = threadIdx.x, wave = t >> 6, lane = t & 63;
    int l15 = lane & 15, quad = lane >> 4;
    int n0 = nb * 128 + wave * 32;     // wave owns 2 m-tiles of 16 rows
    int kv0 = sp * (NTOK / NSPLIT);

    unsigned short* opart = opb + (size_t)sp * ((size_t)BATCH * NTOK * CH);
    float* lpart = lpb + (size_t)sp * (BATCH * NH * NTOK);

    const unsigned short* qbh = qT + ((size_t)(b * NH + h)) * NTOK * HD;
    const unsigned short* kbh = kT + ((size_t)(b * NH + h)) * NTOK * HD;
    const unsigned short* vbh = vv + ((size_t)(b * NH + h)) * HD * NTOK;

    __shared__ __align__(16) unsigned short kbuf[128 * 80];
    __shared__ __align__(16) unsigned short vbuf[64 * 136];

    short8 aQ[2][2];   // B-fragment of QK: B[q-row=l15][hd k=quad*8+j]
    for (int mt = 0; mt < 2; ++mt) {
        aQ[mt][0] = *(const short8*)(qbh + (size_t)(n0 + mt * 16 + l15) * HD + quad * 8);
        aQ[mt][1] = *(const short8*)(qbh + (size_t)(n0 + mt * 16 + l15) * HD + 32 + quad * 8);
    }

    float l_p[2] = {0.f, 0.f};         // per-lane partial denom (q-row = l15)
    float4v o_acc[2][4];
    for (int mt = 0; mt < 2; ++mt)
        for (int ct = 0; ct < 4; ++ct)
            for (int r = 0; r < 4; ++r) o_acc[mt][ct][r] = 0.f;

    for (int ms = kv0; ms < kv0 + NTOK / NSPLIT; ms += 128) {
        __syncthreads();
#pragma unroll
        for (int p = 0; p < 4; ++p) {
            int slot = p * 256 + t;
            int r = slot >> 3, c = slot & 7;
            short8 kd = *(const short8*)(kbh + (size_t)(ms + r) * HD + c * 8);
            *(short8*)(kbuf + r * 80 + c * 8) = kd;
        }
#pragma unroll
        for (int p = 0; p < 4; ++p) {
            int slot = p * 256 + t;
            int r = slot >> 4, c = slot & 15;
            short8 vd = *(const short8*)(vbh + (size_t)r * NTOK + ms + c * 8);
            *(short8*)(vbuf + r * 136 + c * 8) = vd;
        }
        __syncthreads();

#pragma unroll
        for (int kh = 0; kh < 2; ++kh) {      // two 64-key halves
            float4v s[2][4];
#pragma unroll
            for (int nt = 0; nt < 4; ++nt) {
                int krow = kh * 64 + nt * 16 + l15;
                short8 ak0 = *(const short8*)(kbuf + krow * 80 + quad * 8);
                short8 ak1 = *(const short8*)(kbuf + krow * 80 + 32 + quad * 8);
#pragma unroll
                for (int mt = 0; mt < 2; ++mt) {
                    float4v z;
                    for (int r = 0; r < 4; ++r) z[r] = 0.f;
                    z = __builtin_amdgcn_mfma_f32_16x16x32_bf16(ak0, aQ[mt][0], z, 0, 0, 0);
                    z = __builtin_amdgcn_mfma_f32_16x16x32_bf16(ak1, aQ[mt][1], z, 0, 0, 0);
                    s[mt][nt] = z;
                }
            }
            s4bf aP[2][4];
#pragma unroll
            for (int mt = 0; mt < 2; ++mt) {
#pragma unroll
                for (int nt = 0; nt < 4; ++nt) {
                    float e0 = __builtin_amdgcn_exp2f(s[mt][nt][0]);
                    float e1 = __builtin_amdgcn_exp2f(s[mt][nt][1]);
                    float e2 = __builtin_amdgcn_exp2f(s[mt][nt][2]);
                    float e3 = __builtin_amdgcn_exp2f(s[mt][nt][3]);
                    l_p[mt] += (e0 + e1) + (e2 + e3);
                    union { s4bf v; unsigned u[2]; } c;
                    c.u[0] = pk2bf(e0, e1);
                    c.u[1] = pk2bf(e2, e3);
                    aP[mt][nt] = c.v;
                }
            }
#pragma unroll
            for (int ct = 0; ct < 4; ++ct) {
#pragma unroll
                for (int nt = 0; nt < 4; ++nt) {
                    s4bf bv = *(const s4bf*)(vbuf + (ct * 16 + l15) * 136 + kh * 64 + nt * 16 + quad * 4);
#pragma unroll
                    for (int mt = 0; mt < 2; ++mt)
                        o_acc[mt][ct] = __builtin_amdgcn_mfma_f32_16x16x16bf16_1k(aP[mt][nt], bv, o_acc[mt][ct], 0, 0, 0);
                }
            }
        }
    }
    // reduce denom over the 4 quads (key blocks); q-row = l15
    for (int mt = 0; mt < 2; ++mt) {
        l_p[mt] += __shfl_xor(l_p[mt], 16, 64);
        l_p[mt] += __shfl_xor(l_p[mt], 32, 64);
    }
    // store unnormalized partial O (bf16): C-layout col=l15=d, row=quad*4+r=q-row
    for (int mt = 0; mt < 2; ++mt) {
        for (int ct = 0; ct < 4; ++ct) {
            for (int r = 0; r < 4; ++r) {
                int n = n0 + mt * 16 + quad * 4 + r;
                int cg = h * HD + ct * 16 + l15;
                opart[((size_t)b * NTOK + n) * CH + cg] = f2bf(o_acc[mt][ct][r]);
            }
        }
        if (lane < 16)
            lpart[((size_t)(b * NH + h)) * NTOK + n0 + mt * 16 + lane] = l_p[mt];
    }
}

// ---------------- Proj GEMM with fused split-combine + bias + residual ----------------
__global__ __launch_bounds__(256) void proj_gemm(const unsigned short* __restrict__ opb,
        const float* __restrict__ lpb, const unsigned short* __restrict__ wp,
        const float* __restrict__ proj_b, const float* __restrict__ x,
        float* __restrict__ out) {
    int nb = blockIdx.x;   // 0..63
    int cb = blockIdx.y;   // 0..3
    int b  = blockIdx.z;
    int t = threadIdx.x, wave = t >> 6, lane = t & 63;
    int l15 = lane & 15, quad = lane >> 4;
    int c0 = cb * 64 + wave * 16;
    const size_t OP = (size_t)BATCH * NTOK * CH;
    const size_t LP = (size_t)BATCH * NH * NTOK;

    __shared__ __align__(16) unsigned short bt[64 * 264];
    __shared__ float rl[64 * 4];

    short8 aW[8];
    {
        const unsigned short* wr = wp + (size_t)(c0 + l15) * CH + quad * 8;
        for (int kc = 0; kc < 8; ++kc) aW[kc] = *(const short8*)(wr + kc * 32);
    }
    // per-row, per-head reciprocal denominators (normalization must precede channel-sum)
    {
        int r = t >> 2, h = t & 3;
        size_t lidx = ((size_t)(b * NH + h)) * NTOK + nb * 64 + r;
        float ls = (lpb[lidx] + lpb[LP + lidx]) + (lpb[2 * LP + lidx] + lpb[3 * LP + lidx]);
        rl[r * 4 + h] = 1.0f / ls;
    }
    __syncthreads();
    // stage normalized O tile from the 4 split partials
    for (int p = 0; p < 8; ++p) {
        int slot = p * 256 + t;
        int r = slot >> 5, c = slot & 31;
        size_t base = ((size_t)b * NTOK + nb * 64 + r) * CH + c * 8;
        short8 o0 = *(const short8*)(opb + base);
        short8 o1 = *(const short8*)(opb + OP + base);
        short8 o2 = *(const short8*)(opb + 2 * OP + base);
        short8 o3 = *(const short8*)(opb + 3 * OP + base);
        float rinv = rl[r * 4 + (c >> 3)];
        short8 m;
        for (int j = 0; j < 8; ++j) {
            float f = (bf2f((unsigned short)o0[j]) + bf2f((unsigned short)o1[j]))
                    + (bf2f((unsigned short)o2[j]) + bf2f((unsigned short)o3[j]));
            m[j] = (short)f2bf(f * rinv);
        }
        *(short8*)(bt + r * 264 + c * 8) = m;
    }
    __syncthreads();

    float4v acc[4];
    for (int nt = 0; nt < 4; ++nt) for (int r = 0; r < 4; ++r) acc[nt][r] = 0.f;
    for (int kc = 0; kc < 8; ++kc) {
        for (int nt = 0; nt < 4; ++nt) {
            short8 pb = *(const short8*)(bt + (nt * 16 + l15) * 264 + kc * 32 + quad * 8);
            acc[nt] = __builtin_amdgcn_mfma_f32_16x16x32_bf16(aW[kc], pb, acc[nt], 0, 0, 0);
        }
    }
    for (int nt = 0; nt < 4; ++nt) {
        int n = nb * 64 + nt * 16 + l15;
        for (int r = 0; r < 4; ++r) {
            int cc = c0 + quad * 4 + r;
            size_t idx = ((size_t)(b * CH + cc)) * NTOK + n;
            out[idx] = acc[nt][r] + proj_b[cc] + x[idx];
        }
    }
}

extern "C" void kernel_launch(void* const* d_in, const int* in_sizes, int n_in,
                              void* d_out, int out_size, void* d_ws, size_t ws_size,
                              hipStream_t stream) {
    const float* x      = (const float*)d_in[0];
    const float* norm_w = (const float*)d_in[1];
    const float* norm_b = (const float*)d_in[2];
    const float* qkv_w  = (const float*)d_in[3];
    const float* qkv_b  = (const float*)d_in[4];
    const float* proj_w = (const float*)d_in[5];
    const float* proj_b = (const float*)d_in[6];
    float* out = (float*)d_out;

    char* ws = (char*)d_ws;
    float* psum  = (float*)ws;                       // 256 f
    float* psq   = (float*)(ws + 1024);              // 256 f
    float* bqs   = (float*)(ws + 4096);              // 768 f
    unsigned short* wqb = (unsigned short*)(ws + 8192);        // 3*256*256 bf16 -> 401408
    unsigned short* wpb = (unsigned short*)(ws + 401408);      // 256*256 bf16   -> 532480
    float* lpb = (float*)(ws + 532480);              // 4 * 2*4*4096 f = 512 KB
    const size_t MB4 = 4194304;
    unsigned short* hT  = (unsigned short*)(ws + 2097152);     // 4 MB (aliases op slot 0)
    unsigned short* opb = hT;                                  // 4 x 4 MB partials
    unsigned short* qT = (unsigned short*)(ws + 2097152 + 4 * MB4);
    unsigned short* kT = (unsigned short*)(ws + 2097152 + 5 * MB4);
    unsigned short* vv = (unsigned short*)(ws + 2097152 + 6 * MB4);

    prep<<<dim3(512), dim3(256), 0, stream>>>(x, qkv_w, qkv_b, proj_w, psum, psq, wqb, bqs, wpb);
    gn_norm<<<dim3(64, 8, BATCH), dim3(256), 0, stream>>>(x, norm_w, norm_b, psum, psq, hT);
    qkv_gemm<<<dim3(64, 12, BATCH), dim3(256), 0, stream>>>(hT, wqb, bqs, qT, kT, vv);
    attn_kernel<<<dim3(32, NH, BATCH * NSPLIT), dim3(256), 0, stream>>>(qT, kT, vv, opb, lpb);
    proj_gemm<<<dim3(64, 4, BATCH), dim3(256), 0, stream>>>(opb, lpb, wpb, proj_b, x, out);
}